// Round 4
// baseline (260.881 us; speedup 1.0000x reference)
//
#include <hip/hip_runtime.h>
#include <math.h>
#include <stdint.h>

#define BATCH 4096
#define FEAT  1024
#define EDIM  16
#define NDOM  8
#define TDIM  1040   // FEAT + EDIM
#define KP1   1088   // TDIM padded to multiple of 64
#define NLAYER 3
#define EPSV  1e-5f

typedef __attribute__((ext_vector_type(8))) short bf16x8;
typedef __attribute__((ext_vector_type(4))) float f32x4;

__device__ __forceinline__ unsigned short f2bf(float f) {
    union { float f; unsigned int u; } v; v.f = f;
    unsigned int u = v.u;
    return (unsigned short)((u + 0x7fffu + ((u >> 16) & 1u)) >> 16);
}
__device__ __forceinline__ float bf2f(unsigned short u) {
    union { unsigned int u; float f; } v; v.u = ((unsigned int)u) << 16; return v.f;
}
__device__ __forceinline__ void gload_lds16(const void* g, void* l) {
    __builtin_amdgcn_global_load_lds(
        (const __attribute__((address_space(1))) void*)(g),
        (__attribute__((address_space(3))) void*)(l), 16, 0, 0);
}

// 64x64 convert tiles
#define T_W1 136
#define T_W2 32
#define T_W3 8
#define NCONV (T_W1*9 + T_W2*9 + T_W3*9)   // 1584

// ======== kernel 1 "front": converts + grouping + prep (R11-proven) ========
__global__ __launch_bounds__(256) void front(
    const int* __restrict__ dom, int* __restrict__ perm, int* __restrict__ starts,
    const float* __restrict__ cW1, const float* __restrict__ dW1,
    const float* __restrict__ cW2, const float* __restrict__ dW2,
    const float* __restrict__ cW3, const float* __restrict__ dW3,
    unsigned short* __restrict__ Wc1b, unsigned short* __restrict__ Wd1b,
    unsigned short* __restrict__ Wc2b, unsigned short* __restrict__ Wd2b,
    unsigned short* __restrict__ Wc3b, unsigned short* __restrict__ Wd3b,
    const float* __restrict__ x,
    const float* __restrict__ pnw, const float* __restrict__ pnb,
    const float* __restrict__ demb,
    const float* __restrict__ crw, const float* __restrict__ crb,
    const float* __restrict__ aW1, const float* __restrict__ ab1,
    const float* __restrict__ aW2, const float* __restrict__ ab2,
    unsigned short* __restrict__ XCb, float* __restrict__ auxg) {
    int b = blockIdx.x;
    int t = threadIdx.x;

    if (b < NCONV) {
        __shared__ float tile[64][65];
        const float* src; unsigned short* dst; int K, N, Kp, rr;
        if (b < T_W1)            { src = cW1; dst = Wc1b; K = TDIM; N = 512; Kp = KP1; rr = b; }
        else if (b < T_W1*9)     { int r = b - T_W1; int z = r / T_W1; rr = r % T_W1;
                                   src = dW1 + (size_t)z * TDIM * 512; dst = Wd1b + (size_t)z * 512 * KP1;
                                   K = TDIM; N = 512; Kp = KP1; }
        else if (b < T_W1*9+T_W2)   { src = cW2; dst = Wc2b; K = 512; N = 256; Kp = 512; rr = b - T_W1*9; }
        else if (b < T_W1*9+T_W2*9) { int r = b - (T_W1*9+T_W2); int z = r / T_W2; rr = r % T_W2;
                                   src = dW2 + (size_t)z * 512 * 256; dst = Wd2b + (size_t)z * 256 * 512;
                                   K = 512; N = 256; Kp = 512; }
        else if (b < T_W1*9+T_W2*9+T_W3) { src = cW3; dst = Wc3b; K = 256; N = 128; Kp = 256; rr = b - (T_W1*9+T_W2*9); }
        else                     { int r = b - (T_W1*9+T_W2*9+T_W3); int z = r / T_W3; rr = r % T_W3;
                                   src = dW3 + (size_t)z * 256 * 128; dst = Wd3b + (size_t)z * 128 * 256;
                                   K = 256; N = 128; Kp = 256; }
        int kt = Kp >> 6;
        int kb = rr % kt, nb = rr / kt;
        int k0 = kb * 64, n0 = nb * 64;
        #pragma unroll
        for (int i = 0; i < 4; i++) {
            int flat = t + i * 256;
            int kr = flat >> 4, c4 = flat & 15;
            int k = k0 + kr;
            float4 v = make_float4(0.f, 0.f, 0.f, 0.f);
            if (k < K) v = *(const float4*)(src + (size_t)k * N + n0 + c4 * 4);
            tile[kr][c4 * 4 + 0] = v.x;
            tile[kr][c4 * 4 + 1] = v.y;
            tile[kr][c4 * 4 + 2] = v.z;
            tile[kr][c4 * 4 + 3] = v.w;
        }
        __syncthreads();
        #pragma unroll
        for (int i = 0; i < 4; i++) {
            int flat = t + i * 256;
            int n = flat >> 4, kg = flat & 15;
            ushort4 sv;
            sv.x = f2bf(tile[kg * 4 + 0][n]);
            sv.y = f2bf(tile[kg * 4 + 1][n]);
            sv.z = f2bf(tile[kg * 4 + 2][n]);
            sv.w = f2bf(tile[kg * 4 + 3][n]);
            *(ushort4*)(dst + (size_t)(n0 + n) * Kp + k0 + kg * 4) = sv;
        }
        return;
    }
    if (b == NCONV) {
        __shared__ int cnt[NDOM];
        __shared__ int off[NDOM];
        if (t < NDOM) cnt[t] = 0;
        __syncthreads();
        for (int i = t; i < BATCH; i += 256) atomicAdd(&cnt[dom[i]], 1);
        __syncthreads();
        if (t == 0) {
            int s = 0;
            for (int d = 0; d < NDOM; d++) { off[d] = s; starts[d] = s; s += cnt[d]; }
            starts[NDOM] = s;
        }
        __syncthreads();
        for (int i = t; i < BATCH; i += 256) {
            int p = atomicAdd(&off[dom[i]], 1);
            perm[p] = i;
        }
        return;
    }

    // ---- prep: one wave per row, row in registers, barrier-free ----
    int w = t >> 6, lane = t & 63;
    int row = (b - NCONV - 1) * 4 + w;
    int d = dom[row];

    float4 X[4];
    #pragma unroll
    for (int j = 0; j < 4; j++)
        X[j] = *(const float4*)(x + (size_t)row * FEAT + 4 * lane + 256 * j);

    float s = 0.f, ss = 0.f;
    #pragma unroll
    for (int j = 0; j < 4; j++) {
        s  += X[j].x + X[j].y + X[j].z + X[j].w;
        ss += X[j].x*X[j].x + X[j].y*X[j].y + X[j].z*X[j].z + X[j].w*X[j].w;
    }
    #pragma unroll
    for (int m = 1; m < 64; m <<= 1) {
        s  += __shfl_xor(s,  m);
        ss += __shfl_xor(ss, m);
    }
    float mean = s / (float)FEAT;
    float var  = ss / (float)FEAT - mean * mean;
    float rstd = rsqrtf(var + EPSV);

    float4 x0[4], xc[4];
    #pragma unroll
    for (int j = 0; j < 4; j++) {
        float4 wv = *(const float4*)(pnw + (size_t)d * FEAT + 4 * lane + 256 * j);
        float4 bv = *(const float4*)(pnb + (size_t)d * FEAT + 4 * lane + 256 * j);
        x0[j].x = (X[j].x - mean) * rstd * wv.x + bv.x;
        x0[j].y = (X[j].y - mean) * rstd * wv.y + bv.y;
        x0[j].z = (X[j].z - mean) * rstd * wv.z + bv.z;
        x0[j].w = (X[j].w - mean) * rstd * wv.w + bv.w;
        xc[j] = x0[j];
    }
    float x0e = 0.f, xce = 0.f;
    if (lane < EDIM) { x0e = demb[d * EDIM + lane]; xce = x0e; }

    #pragma unroll
    for (int l = 0; l < NLAYER; l++) {
        const float* wl = crw + l * TDIM;
        const float* bl = crb + l * TDIM;
        float partial = 0.f;
        #pragma unroll
        for (int j = 0; j < 4; j++) {
            float4 wv = *(const float4*)(wl + 4 * lane + 256 * j);
            partial += xc[j].x*wv.x + xc[j].y*wv.y + xc[j].z*wv.z + xc[j].w*wv.w;
        }
        if (lane < EDIM) partial += xce * wl[FEAT + lane];
        #pragma unroll
        for (int m = 1; m < 64; m <<= 1) partial += __shfl_xor(partial, m);
        float proj = partial;
        #pragma unroll
        for (int j = 0; j < 4; j++) {
            float4 bv = *(const float4*)(bl + 4 * lane + 256 * j);
            xc[j].x = fmaf(x0[j].x, proj, bv.x + xc[j].x);
            xc[j].y = fmaf(x0[j].y, proj, bv.y + xc[j].y);
            xc[j].z = fmaf(x0[j].z, proj, bv.z + xc[j].z);
            xc[j].w = fmaf(x0[j].w, proj, bv.w + xc[j].w);
        }
        if (lane < EDIM) xce = fmaf(x0e, proj, bl[FEAT + lane] + xce);
    }

    #pragma unroll
    for (int j = 0; j < 4; j++) {
        ushort4 sv;
        sv.x = f2bf(xc[j].x); sv.y = f2bf(xc[j].y);
        sv.z = f2bf(xc[j].z); sv.w = f2bf(xc[j].w);
        *(ushort4*)(XCb + (size_t)row * KP1 + 4 * lane + 256 * j) = sv;
    }
    XCb[(size_t)row * KP1 + FEAT + lane] = (lane < EDIM) ? f2bf(xce) : 0;

    float h = (lane < 32) ? ab1[lane] : 0.f;
    #pragma unroll
    for (int e = 0; e < EDIM; e++) {
        float ev = __shfl(xce, e);
        if (lane < 32) h = fmaf(ev, aW1[e * 32 + lane], h);
    }
    float c = (lane < 32) ? fmaxf(h, 0.f) * aW2[lane] : 0.f;
    #pragma unroll
    for (int m = 1; m < 64; m <<= 1) c += __shfl_xor(c, m);
    if (lane == 0) auxg[row] = c + ab2[0];
}

// ======== L1 GEMM, chain-fused + double-buffered 2-phase ========
// 128 perm-rows x (64 center + 64 domain) cols per block; A staged once,
// shared by both chains. 2-phase: stage tile t+1 before MFMA of tile t,
// one barrier per tile (proven schedule from tail_fused). LDS 64KB.
// Grid (256, 8): x = m-slot so wgid%8 = sl%8 -> all 8 n-blocks of an m-slot
// land on one XCD => A-tile L2-resident after first fetch (T1 locality).
__global__ __launch_bounds__(256) void gemm_l1_fused(
    const unsigned short* __restrict__ A,    // XCb [BATCH][KP1]
    const unsigned short* __restrict__ Wc,   // Wc1b [512][KP1]
    const unsigned short* __restrict__ Wd,   // Wd1b [D][512][KP1]
    const float* __restrict__ bc, const float* __restrict__ bd,
    unsigned short* __restrict__ Cc, unsigned short* __restrict__ Cd, // perm-space [BATCH][512]
    const int* __restrict__ starts, const int* __restrict__ perm) {
    __shared__ short As[2][128 * 64];   // 2 x 16KB
    __shared__ short Bs[2][128 * 64];   // 2 x 16KB

    int xb = blockIdx.x;               // m-index
    int d = xb >> 5, sl = xb & 31;
    int ds = starts[d], de = starts[d + 1];
    int m0 = ds + sl * 128;
    if (m0 >= de) return;
    int mEnd = de;
    int n0 = blockIdx.y * 64;          // column base within each chain's 512

    int tid = threadIdx.x;
    int w = tid >> 6, lane = tid & 63;
    int wm = w >> 1, wn = w & 1;       // wn=0 -> center cols, wn=1 -> domain cols
    int lr = lane & 15, q = lane >> 4;

    const unsigned short* pA[4]; int sA[4];
    const unsigned short* pB[4]; int sB[4];
    #pragma unroll
    for (int i = 0; i < 4; i++) {
        int seg = i * 4 + w;
        int ch = seg * 64 + lane;          // [0,1024)
        int loc = ch >> 3, c = ch & 7;     // loc: A row 0..127
        int mm = m0 + loc; if (mm > mEnd - 1) mm = mEnd - 1;
        int rowp = perm[mm];
        pA[i] = A + (size_t)rowp * KP1 + ((c ^ (loc & 7)) << 3);
        sA[i] = seg * 512;
    }
    #pragma unroll
    for (int i = 0; i < 4; i++) {
        int seg = i * 4 + w;
        int ch = seg * 64 + lane;
        int loc = ch >> 3, c = ch & 7;     // loc: B row 0..127
        const unsigned short* base = (loc < 64)
            ? (Wc + (size_t)(n0 + loc) * KP1)
            : (Wd + ((size_t)d * 512 + n0 + (loc - 64)) * KP1);
        pB[i] = base + ((c ^ (loc & 7)) << 3);
        sB[i] = seg * 512;
    }

    f32x4 acc[4][4];
    #pragma unroll
    for (int i = 0; i < 4; i++)
        #pragma unroll
        for (int j = 0; j < 4; j++)
            acc[i][j] = (f32x4){0.f, 0.f, 0.f, 0.f};

    // prologue: stage k-tile 0 into buffer 0
    #pragma unroll
    for (int i = 0; i < 4; i++) gload_lds16(pA[i], As[0] + sA[i]);
    #pragma unroll
    for (int i = 0; i < 4; i++) gload_lds16(pB[i], Bs[0] + sB[i]);
    __syncthreads();

    #pragma unroll 1
    for (int ks = 0; ks < KP1 / 64; ks++) {
        int cur = ks & 1, nxt = cur ^ 1;
        if (ks < KP1 / 64 - 1) {
            int k0 = (ks + 1) * 64;
            #pragma unroll
            for (int i = 0; i < 4; i++) gload_lds16(pA[i] + k0, As[nxt] + sA[i]);
            #pragma unroll
            for (int i = 0; i < 4; i++) gload_lds16(pB[i] + k0, Bs[nxt] + sB[i]);
        }
        #pragma unroll
        for (int half = 0; half < 2; half++) {
            int cc = half * 4 + q;
            bf16x8 af[4], bf[4];
            #pragma unroll
            for (int i = 0; i < 4; i++) {
                int m = wm * 64 + i * 16 + lr;
                af[i] = *(const bf16x8*)(As[cur] + m * 64 + ((cc ^ (m & 7)) << 3));
            }
            #pragma unroll
            for (int j = 0; j < 4; j++) {
                int n = wn * 64 + j * 16 + lr;
                bf[j] = *(const bf16x8*)(Bs[cur] + n * 64 + ((cc ^ (n & 7)) << 3));
            }
            #pragma unroll
            for (int i = 0; i < 4; i++)
                #pragma unroll
                for (int j = 0; j < 4; j++)
                    acc[i][j] = __builtin_amdgcn_mfma_f32_16x16x32_bf16(
                        af[i], bf[j], acc[i][j], 0, 0, 0);
        }
        __syncthreads();   // drains vmcnt -> buffer 'nxt' ready for next iter
    }

    const float* bias = wn ? (bd + d * 512) : bc;
    unsigned short* C = wn ? Cd : Cc;
    #pragma unroll
    for (int i = 0; i < 4; i++) {
        #pragma unroll
        for (int j = 0; j < 4; j++) {
            int col = n0 + j * 16 + lr;
            float bvv = bias[col];
            int rowb = m0 + wm * 64 + i * 16 + q * 4;
            #pragma unroll
            for (int r = 0; r < 4; r++) {
                int row = rowb + r;
                if (row >= mEnd) continue;
                C[(size_t)row * 512 + col] = f2bf(fmaxf(acc[i][j][r] + bvv, 0.f));
            }
        }
    }
}

// ======== fused tail: L2 + L3 + STAR + final MLP + sigmoid, one kernel ========
// Decode d = wgid%8 so XCD = d: one domain per XCD, W2[d]/W3[d] fetched once
// per XCD and L2-resident for all its slots (T1 locality).
__global__ __launch_bounds__(256) void tail_fused(
    const unsigned short* __restrict__ H1c, const unsigned short* __restrict__ H1d,
    const unsigned short* __restrict__ Wc2, const unsigned short* __restrict__ Wd2,
    const float* __restrict__ cb2v, const float* __restrict__ db2v,
    const unsigned short* __restrict__ Wc3, const unsigned short* __restrict__ Wd3,
    const float* __restrict__ cb3v, const float* __restrict__ db3v,
    const float* __restrict__ fW1, const float* __restrict__ fb1,
    const float* __restrict__ fW2, const float* __restrict__ fb2,
    const float* __restrict__ auxg, const int* __restrict__ perm,
    const int* __restrict__ starts, float* __restrict__ out) {

    __shared__ __align__(16) char smem[98304];
    short* Bsb[2] = { (short*)smem, (short*)(smem + 32768) };          // 2 x 32KB (B tiles)
    short* Asb[2] = { (short*)(smem + 65536), (short*)(smem + 69632) };// 2 x 4KB  (A tiles)
    short* H2    = (short*)(smem + 73728);                             // 16KB [32][256] swizzled
    short* fused = (short*)(smem + 90112);                             // 8KB  [32][128] swizzled

    int y = blockIdx.x;
    int d = y & 7, sl = y >> 3;        // XCD = wgid%8 = d
    int ds = starts[d], de = starts[d + 1];
    int m0 = ds + sl * 32;
    if (m0 >= de) return;
    int mEnd = de;

    int tid = threadIdx.x;
    int w = tid >> 6, lane = tid & 63;
    int lr = lane & 15, q = lane >> 4;

    // staging geometry: thread handles chunk ch = seg*64+lane; row = seg*8+(lane>>3)
    int bn = w * 8 + (lane >> 3);                 // base row (0..31) for seg=w
    int sw = ((lane & 7) ^ (bn & 7)) << 3;        // pre-swizzled chunk offset (shorts)
    int rowA = m0 + bn; if (rowA > mEnd - 1) rowA = mEnd - 1;

    const unsigned short* pA0  = H1c + (size_t)rowA * 512 + sw;
    const unsigned short* pA1  = H1d + (size_t)rowA * 512 + sw;
    const unsigned short* pW20 = Wc2 + (size_t)bn * 512 + sw;
    const unsigned short* pW21 = Wd2 + (size_t)d * 256 * 512 + (size_t)bn * 512 + sw;
    const unsigned short* pW30 = Wc3 + (size_t)bn * 256 + sw;
    const unsigned short* pW31 = Wd3 + (size_t)d * 128 * 256 + (size_t)bn * 256 + sw;

    auto stage_l2 = [&](int c, int k0, int pb) {
        const unsigned short* pa = c ? pA1 : pA0;
        const unsigned short* pw = c ? pW21 : pW20;
        gload_lds16(pa + k0, Asb[pb] + w * 512);
        #pragma unroll
        for (int i = 0; i < 8; i++)
            gload_lds16(pw + (size_t)i * 32 * 512 + k0, Bsb[pb] + (i * 4 + w) * 512);
    };
    auto stage_l3 = [&](int c, int k0, int pb) {
        const unsigned short* pw = c ? pW31 : pW30;
        #pragma unroll
        for (int i = 0; i < 4; i++)
            gload_lds16(pw + (size_t)i * 32 * 256 + k0, Bsb[pb] + (i * 4 + w) * 512);
    };

    // prologue: tile 0 (chain0 L2 k0=0)
    stage_l2(0, 0, 0);
    __syncthreads();

    #pragma unroll
    for (int c = 0; c < 2; c++) {
        // ---- L2: 32 x 256, K=512, 8 tiles ----
        f32x4 acc2[2][4];
        #pragma unroll
        for (int i = 0; i < 2; i++)
            #pragma unroll
            for (int j = 0; j < 4; j++) acc2[i][j] = (f32x4){0.f, 0.f, 0.f, 0.f};

        #pragma unroll
        for (int it = 0; it < 8; it++) {
            int t = c * 12 + it;
            int pb = t & 1, pn = pb ^ 1;
            if (it < 7) stage_l2(c, (it + 1) * 64, pn);
            else        stage_l3(c, 0, pn);

            #pragma unroll
            for (int half = 0; half < 2; half++) {
                int cc = half * 4 + q;
                bf16x8 af[2], bf[4];
                #pragma unroll
                for (int i = 0; i < 2; i++) {
                    int m = i * 16 + lr;
                    af[i] = *(const bf16x8*)(Asb[pb] + m * 64 + ((cc ^ (m & 7)) << 3));
                }
                #pragma unroll
                for (int j = 0; j < 4; j++) {
                    int n = w * 64 + j * 16 + lr;
                    bf[j] = *(const bf16x8*)(Bsb[pb] + n * 64 + ((cc ^ (n & 7)) << 3));
                }
                #pragma unroll
                for (int i = 0; i < 2; i++)
                    #pragma unroll
                    for (int j = 0; j < 4; j++)
                        acc2[i][j] = __builtin_amdgcn_mfma_f32_16x16x32_bf16(
                            af[i], bf[j], acc2[i][j], 0, 0, 0);
            }
            __syncthreads();
        }

        // L2 epilogue: bias + relu -> H2 LDS (swizzled for MFMA-A reads)
        const float* b2 = c ? (db2v + d * 256) : cb2v;
        #pragma unroll
        for (int i = 0; i < 2; i++)
            #pragma unroll
            for (int j = 0; j < 4; j++) {
                int col = w * 64 + j * 16 + lr;
                float bv = b2[col];
                int cch = col >> 3;
                #pragma unroll
                for (int r = 0; r < 4; r++) {
                    int row = i * 16 + q * 4 + r;
                    int pc = (cch & 24) | ((cch ^ (row & 7)) & 7);
                    float v = fmaxf(acc2[i][j][r] + bv, 0.f);
                    H2[row * 256 + pc * 8 + (col & 7)] = (short)f2bf(v);
                }
            }
        __syncthreads();

        // ---- L3: 32 x 128, K=256, 4 tiles; A = H2 (LDS) ----
        f32x4 acc3[2][2];
        #pragma unroll
        for (int i = 0; i < 2; i++)
            #pragma unroll
            for (int j = 0; j < 2; j++) acc3[i][j] = (f32x4){0.f, 0.f, 0.f, 0.f};

        #pragma unroll
        for (int it = 0; it < 4; it++) {
            int t = c * 12 + 8 + it;
            int pb = t & 1, pn = pb ^ 1;
            if (it < 3)      stage_l3(c, (it + 1) * 64, pn);
            else if (c == 0) stage_l2(1, 0, pn);

            #pragma unroll
            for (int half = 0; half < 2; half++) {
                int cc = half * 4 + q;
                int C = it * 8 + cc;   // global k-chunk in [0,32)
                bf16x8 af[2], bf[2];
                #pragma unroll
                for (int i = 0; i < 2; i++) {
                    int m = i * 16 + lr;
                    int pcm = (C & 24) | ((C ^ (m & 7)) & 7);
                    af[i] = *(const bf16x8*)(H2 + m * 256 + pcm * 8);
                }
                #pragma unroll
                for (int j = 0; j < 2; j++) {
                    int n = w * 32 + j * 16 + lr;
                    bf[j] = *(const bf16x8*)(Bsb[pb] + n * 64 + ((cc ^ (n & 7)) << 3));
                }
                #pragma unroll
                for (int i = 0; i < 2; i++)
                    #pragma unroll
                    for (int j = 0; j < 2; j++)
                        acc3[i][j] = __builtin_amdgcn_mfma_f32_16x16x32_bf16(
                            af[i], bf[j], acc3[i][j], 0, 0, 0);
            }
            __syncthreads();
        }

        // L3 epilogue -> fused (chain0: stash; chain1: STAR tanh-combine)
        const float* b3 = c ? (db3v + d * 128) : cb3v;
        #pragma unroll
        for (int i = 0; i < 2; i++)
            #pragma unroll
            for (int j = 0; j < 2; j++) {
                int col = w * 32 + j * 16 + lr;
                float bv = b3[col];
                int cch = col >> 3;
                #pragma unroll
                for (int r = 0; r < 4; r++) {
                    int row = i * 16 + q * 4 + r;
                    int pc = (cch & 8) | ((cch ^ (row & 7)) & 7);
                    int idx = row * 128 + pc * 8 + (col & 7);
                    if (c == 0) {
                        fused[idx] = (short)f2bf(acc3[i][j][r] + bv);
                    } else {
                        float cv = bf2f((unsigned short)fused[idx]);
                        fused[idx] = (short)f2bf(cv * tanhf(acc3[i][j][r] + bv));
                    }
                }
            }
        __syncthreads();
    }

    // ---- final MLP (R7-proven epilogue): (32x128)@(128x64) relu @ (64x1) + sigmoid ----
    short* Bsf = Bsb[0];
    float* Ls  = (float*)Asb[0];
    for (int s2 = tid; s2 < 1024; s2 += 256) {
        int n = s2 >> 4, cch = s2 & 15;
        bf16x8 vv;
        #pragma unroll
        for (int kk = 0; kk < 8; kk++)
            vv[kk] = (short)f2bf(fW1[(cch * 8 + kk) * 64 + n]);
        int pc = (cch & 8) | ((cch ^ (n & 7)) & 7);
        *(bf16x8*)(Bsf + n * 128 + pc * 8) = vv;
    }
    __syncthreads();

    int wm = w >> 1, wn = w & 1;
    f32x4 acc2f[2];
    #pragma unroll
    for (int j = 0; j < 2; j++) acc2f[j] = (f32x4){0.f, 0.f, 0.f, 0.f};
    #pragma unroll
    for (int g = 0; g < 4; g++) {
        int cc = g * 4 + q;
        int m = wm * 16 + lr;
        int pcm = (cc & 8) | ((cc ^ (m & 7)) & 7);
        bf16x8 af = *(const bf16x8*)(fused + m * 128 + pcm * 8);
        #pragma unroll
        for (int j = 0; j < 2; j++) {
            int n = wn * 32 + j * 16 + lr;
            int pcn = (cc & 8) | ((cc ^ (n & 7)) & 7);
            bf16x8 bf = *(const bf16x8*)(Bsf + n * 128 + pcn * 8);
            acc2f[j] = __builtin_amdgcn_mfma_f32_16x16x32_bf16(af, bf, acc2f[j], 0, 0, 0);
        }
    }

    float w2v[2], b1v[2];
    #pragma unroll
    for (int j = 0; j < 2; j++) {
        int col = wn * 32 + j * 16 + lr;
        w2v[j] = fW2[col];
        b1v[j] = fb1[col];
    }
    float rowv[4];
    #pragma unroll
    for (int r = 0; r < 4; r++) {
        float v = 0.f;
        #pragma unroll
        for (int j = 0; j < 2; j++)
            v += fmaxf(acc2f[j][r] + b1v[j], 0.f) * w2v[j];
        v += __shfl_xor(v, 1);
        v += __shfl_xor(v, 2);
        v += __shfl_xor(v, 4);
        v += __shfl_xor(v, 8);
        rowv[r] = v;
    }
    if (wn == 0 && lr == 0) {
        #pragma unroll
        for (int r = 0; r < 4; r++)
            Ls[wm * 16 + q * 4 + r] = rowv[r];
    }
    __syncthreads();
    if (wn == 1 && lr == 0) {
        float b2 = fb2[0];
        #pragma unroll
        for (int r = 0; r < 4; r++) {
            int row = wm * 16 + q * 4 + r;
            int p = m0 + row;
            if (p < mEnd) {
                int orow = perm[p];
                float logit = Ls[row] + rowv[r] + b2 + auxg[orow];
                out[orow] = 1.f / (1.f + expf(-logit));
            }
        }
    }
}

extern "C" void kernel_launch(void* const* d_in, const int* in_sizes, int n_in,
                              void* d_out, int out_size, void* d_ws, size_t ws_size,
                              hipStream_t stream) {
    (void)in_sizes; (void)n_in; (void)out_size; (void)ws_size;

    const float* x    = (const float*)d_in[0];
    const int*   dom  = (const int*)  d_in[1];
    const float* pnw  = (const float*)d_in[2];
    const float* pnb  = (const float*)d_in[3];
    const float* demb = (const float*)d_in[4];
    const float* crw  = (const float*)d_in[5];
    const float* crb  = (const float*)d_in[6];
    const float* cW1  = (const float*)d_in[7];
    const float* cb1  = (const float*)d_in[8];
    const float* cW2  = (const float*)d_in[9];
    const float* cb2  = (const float*)d_in[10];
    const float* cW3  = (const float*)d_in[11];
    const float* cb3  = (const float*)d_in[12];
    const float* dW1  = (const float*)d_in[13];
    const float* db1  = (const float*)d_in[14];
    const float* dW2  = (const float*)d_in[15];
    const float* db2  = (const float*)d_in[16];
    const float* dW3  = (const float*)d_in[17];
    const float* db3  = (const float*)d_in[18];
    const float* fW1  = (const float*)d_in[19];
    const float* fb1  = (const float*)d_in[20];
    const float* fW2  = (const float*)d_in[21];
    const float* fb2  = (const float*)d_in[22];
    const float* aW1  = (const float*)d_in[23];
    const float* ab1  = (const float*)d_in[24];
    const float* aW2  = (const float*)d_in[25];
    const float* ab2  = (const float*)d_in[26];
    float* out = (float*)d_out;

    char* base = (char*)d_ws;
    size_t o = 0;
    auto alloc = [&](size_t bytes) { char* p = base + o; o += (bytes + 255) & ~size_t(255); return p; };

    int* perm   = (int*)alloc(BATCH * 4);
    int* starts = (int*)alloc((NDOM + 1) * 4);
    float* auxg = (float*)alloc(BATCH * 4);
    unsigned short* XCb  = (unsigned short*)alloc((size_t)BATCH * KP1 * 2);
    unsigned short* H1c  = (unsigned short*)alloc((size_t)BATCH * 512 * 2);
    unsigned short* H1d  = (unsigned short*)alloc((size_t)BATCH * 512 * 2);
    unsigned short* Wc1b = (unsigned short*)alloc((size_t)512 * KP1 * 2);
    unsigned short* Wd1b = (unsigned short*)alloc((size_t)NDOM * 512 * KP1 * 2);
    unsigned short* Wc2b = (unsigned short*)alloc((size_t)256 * 512 * 2);
    unsigned short* Wd2b = (unsigned short*)alloc((size_t)NDOM * 256 * 512 * 2);
    unsigned short* Wc3b = (unsigned short*)alloc((size_t)128 * 256 * 2);
    unsigned short* Wd3b = (unsigned short*)alloc((size_t)NDOM * 128 * 256 * 2);

    // 1) convert + grouping + prep (one launch)
    front<<<NCONV + 1 + BATCH / 4, 256, 0, stream>>>(
        dom, perm, starts, cW1, dW1, cW2, dW2, cW3, dW3,
        Wc1b, Wd1b, Wc2b, Wd2b, Wc3b, Wd3b,
        x, pnw, pnb, demb, crw, crb, aW1, ab1, aW2, ab2, XCb, auxg);

    // 2) L1 chain-fused, double-buffered: grid (m-slots, n-blocks) so that
    //    same-A blocks share an XCD (wgid%8 = sl%8)
    gemm_l1_fused<<<dim3(NDOM * 32, 8), 256, 0, stream>>>(
        XCb, Wc1b, Wd1b, cb1, db1, H1c, H1d, starts, perm);

    // 3) fused tail: L2 + L3 + STAR + final MLP + sigmoid (32-row slots),
    //    d = wgid%8 so one domain's weights stay in one XCD's L2
    tail_fused<<<NDOM * 128, 256, 0, stream>>>(
        H1c, H1d, Wc2b, Wd2b, cb2, db2, Wc3b, Wd3b, cb3, db3,
        fW1, fb1, fW2, fb2, auxg, perm, starts, out);
}

// Round 5
// 197.886 us; speedup vs baseline: 1.3183x; 1.3183x over previous
//
#include <hip/hip_runtime.h>
#include <math.h>
#include <stdint.h>

#define BATCH 4096
#define FEAT  1024
#define EDIM  16
#define NDOM  8
#define TDIM  1040   // FEAT + EDIM
#define KP1   1088   // TDIM padded to multiple of 64
#define NLAYER 3
#define EPSV  1e-5f

typedef __attribute__((ext_vector_type(8))) short bf16x8;
typedef __attribute__((ext_vector_type(4))) float f32x4;

__device__ __forceinline__ unsigned short f2bf(float f) {
    union { float f; unsigned int u; } v; v.f = f;
    unsigned int u = v.u;
    return (unsigned short)((u + 0x7fffu + ((u >> 16) & 1u)) >> 16);
}
__device__ __forceinline__ float bf2f(unsigned short u) {
    union { unsigned int u; float f; } v; v.u = ((unsigned int)u) << 16; return v.f;
}
__device__ __forceinline__ void gload_lds16(const void* g, void* l) {
    __builtin_amdgcn_global_load_lds(
        (const __attribute__((address_space(1))) void*)(g),
        (__attribute__((address_space(3))) void*)(l), 16, 0, 0);
}

// 64x64 convert tiles
#define T_W1 136
#define T_W2 32
#define T_W3 8
#define NCONV (T_W1*9 + T_W2*9 + T_W3*9)   // 1584

// ======== kernel 1 "front": converts + grouping + prep (R11-proven) ========
__global__ __launch_bounds__(256) void front(
    const int* __restrict__ dom, int* __restrict__ perm, int* __restrict__ starts,
    const float* __restrict__ cW1, const float* __restrict__ dW1,
    const float* __restrict__ cW2, const float* __restrict__ dW2,
    const float* __restrict__ cW3, const float* __restrict__ dW3,
    unsigned short* __restrict__ Wc1b, unsigned short* __restrict__ Wd1b,
    unsigned short* __restrict__ Wc2b, unsigned short* __restrict__ Wd2b,
    unsigned short* __restrict__ Wc3b, unsigned short* __restrict__ Wd3b,
    const float* __restrict__ x,
    const float* __restrict__ pnw, const float* __restrict__ pnb,
    const float* __restrict__ demb,
    const float* __restrict__ crw, const float* __restrict__ crb,
    const float* __restrict__ aW1, const float* __restrict__ ab1,
    const float* __restrict__ aW2, const float* __restrict__ ab2,
    unsigned short* __restrict__ XCb, float* __restrict__ auxg) {
    int b = blockIdx.x;
    int t = threadIdx.x;

    if (b < NCONV) {
        __shared__ float tile[64][65];
        const float* src; unsigned short* dst; int K, N, Kp, rr;
        if (b < T_W1)            { src = cW1; dst = Wc1b; K = TDIM; N = 512; Kp = KP1; rr = b; }
        else if (b < T_W1*9)     { int r = b - T_W1; int z = r / T_W1; rr = r % T_W1;
                                   src = dW1 + (size_t)z * TDIM * 512; dst = Wd1b + (size_t)z * 512 * KP1;
                                   K = TDIM; N = 512; Kp = KP1; }
        else if (b < T_W1*9+T_W2)   { src = cW2; dst = Wc2b; K = 512; N = 256; Kp = 512; rr = b - T_W1*9; }
        else if (b < T_W1*9+T_W2*9) { int r = b - (T_W1*9+T_W2); int z = r / T_W2; rr = r % T_W2;
                                   src = dW2 + (size_t)z * 512 * 256; dst = Wd2b + (size_t)z * 256 * 512;
                                   K = 512; N = 256; Kp = 512; }
        else if (b < T_W1*9+T_W2*9+T_W3) { src = cW3; dst = Wc3b; K = 256; N = 128; Kp = 256; rr = b - (T_W1*9+T_W2*9); }
        else                     { int r = b - (T_W1*9+T_W2*9+T_W3); int z = r / T_W3; rr = r % T_W3;
                                   src = dW3 + (size_t)z * 256 * 128; dst = Wd3b + (size_t)z * 128 * 256;
                                   K = 256; N = 128; Kp = 256; }
        int kt = Kp >> 6;
        int kb = rr % kt, nb = rr / kt;
        int k0 = kb * 64, n0 = nb * 64;
        #pragma unroll
        for (int i = 0; i < 4; i++) {
            int flat = t + i * 256;
            int kr = flat >> 4, c4 = flat & 15;
            int k = k0 + kr;
            float4 v = make_float4(0.f, 0.f, 0.f, 0.f);
            if (k < K) v = *(const float4*)(src + (size_t)k * N + n0 + c4 * 4);
            tile[kr][c4 * 4 + 0] = v.x;
            tile[kr][c4 * 4 + 1] = v.y;
            tile[kr][c4 * 4 + 2] = v.z;
            tile[kr][c4 * 4 + 3] = v.w;
        }
        __syncthreads();
        #pragma unroll
        for (int i = 0; i < 4; i++) {
            int flat = t + i * 256;
            int n = flat >> 4, kg = flat & 15;
            ushort4 sv;
            sv.x = f2bf(tile[kg * 4 + 0][n]);
            sv.y = f2bf(tile[kg * 4 + 1][n]);
            sv.z = f2bf(tile[kg * 4 + 2][n]);
            sv.w = f2bf(tile[kg * 4 + 3][n]);
            *(ushort4*)(dst + (size_t)(n0 + n) * Kp + k0 + kg * 4) = sv;
        }
        return;
    }
    if (b == NCONV) {
        __shared__ int cnt[NDOM];
        __shared__ int off[NDOM];
        if (t < NDOM) cnt[t] = 0;
        __syncthreads();
        for (int i = t; i < BATCH; i += 256) atomicAdd(&cnt[dom[i]], 1);
        __syncthreads();
        if (t == 0) {
            int s = 0;
            for (int d = 0; d < NDOM; d++) { off[d] = s; starts[d] = s; s += cnt[d]; }
            starts[NDOM] = s;
        }
        __syncthreads();
        for (int i = t; i < BATCH; i += 256) {
            int p = atomicAdd(&off[dom[i]], 1);
            perm[p] = i;
        }
        return;
    }

    // ---- prep: one wave per row, row in registers, barrier-free ----
    int w = t >> 6, lane = t & 63;
    int row = (b - NCONV - 1) * 4 + w;
    int d = dom[row];

    float4 X[4];
    #pragma unroll
    for (int j = 0; j < 4; j++)
        X[j] = *(const float4*)(x + (size_t)row * FEAT + 4 * lane + 256 * j);

    float s = 0.f, ss = 0.f;
    #pragma unroll
    for (int j = 0; j < 4; j++) {
        s  += X[j].x + X[j].y + X[j].z + X[j].w;
        ss += X[j].x*X[j].x + X[j].y*X[j].y + X[j].z*X[j].z + X[j].w*X[j].w;
    }
    #pragma unroll
    for (int m = 1; m < 64; m <<= 1) {
        s  += __shfl_xor(s,  m);
        ss += __shfl_xor(ss, m);
    }
    float mean = s / (float)FEAT;
    float var  = ss / (float)FEAT - mean * mean;
    float rstd = rsqrtf(var + EPSV);

    float4 x0[4], xc[4];
    #pragma unroll
    for (int j = 0; j < 4; j++) {
        float4 wv = *(const float4*)(pnw + (size_t)d * FEAT + 4 * lane + 256 * j);
        float4 bv = *(const float4*)(pnb + (size_t)d * FEAT + 4 * lane + 256 * j);
        x0[j].x = (X[j].x - mean) * rstd * wv.x + bv.x;
        x0[j].y = (X[j].y - mean) * rstd * wv.y + bv.y;
        x0[j].z = (X[j].z - mean) * rstd * wv.z + bv.z;
        x0[j].w = (X[j].w - mean) * rstd * wv.w + bv.w;
        xc[j] = x0[j];
    }
    float x0e = 0.f, xce = 0.f;
    if (lane < EDIM) { x0e = demb[d * EDIM + lane]; xce = x0e; }

    #pragma unroll
    for (int l = 0; l < NLAYER; l++) {
        const float* wl = crw + l * TDIM;
        const float* bl = crb + l * TDIM;
        float partial = 0.f;
        #pragma unroll
        for (int j = 0; j < 4; j++) {
            float4 wv = *(const float4*)(wl + 4 * lane + 256 * j);
            partial += xc[j].x*wv.x + xc[j].y*wv.y + xc[j].z*wv.z + xc[j].w*wv.w;
        }
        if (lane < EDIM) partial += xce * wl[FEAT + lane];
        #pragma unroll
        for (int m = 1; m < 64; m <<= 1) partial += __shfl_xor(partial, m);
        float proj = partial;
        #pragma unroll
        for (int j = 0; j < 4; j++) {
            float4 bv = *(const float4*)(bl + 4 * lane + 256 * j);
            xc[j].x = fmaf(x0[j].x, proj, bv.x + xc[j].x);
            xc[j].y = fmaf(x0[j].y, proj, bv.y + xc[j].y);
            xc[j].z = fmaf(x0[j].z, proj, bv.z + xc[j].z);
            xc[j].w = fmaf(x0[j].w, proj, bv.w + xc[j].w);
        }
        if (lane < EDIM) xce = fmaf(x0e, proj, bl[FEAT + lane] + xce);
    }

    #pragma unroll
    for (int j = 0; j < 4; j++) {
        ushort4 sv;
        sv.x = f2bf(xc[j].x); sv.y = f2bf(xc[j].y);
        sv.z = f2bf(xc[j].z); sv.w = f2bf(xc[j].w);
        *(ushort4*)(XCb + (size_t)row * KP1 + 4 * lane + 256 * j) = sv;
    }
    XCb[(size_t)row * KP1 + FEAT + lane] = (lane < EDIM) ? f2bf(xce) : 0;

    float h = (lane < 32) ? ab1[lane] : 0.f;
    #pragma unroll
    for (int e = 0; e < EDIM; e++) {
        float ev = __shfl(xce, e);
        if (lane < 32) h = fmaf(ev, aW1[e * 32 + lane], h);
    }
    float c = (lane < 32) ? fmaxf(h, 0.f) * aW2[lane] : 0.f;
    #pragma unroll
    for (int m = 1; m < 64; m <<= 1) c += __shfl_xor(c, m);
    if (lane == 0) auxg[row] = c + ab2[0];
}

// ======== L1 GEMM, chain-fused, 64m x 128n tiles, double-buffered ========
// R4 post-mortem: 128-row slots left ~4 useful slots/domain -> useful wgid%8
// stuck in {0..3} (half the XCDs idle) + 64KB LDS -> no TLP -> 102us.
// Fix: 64-row m-tiles -> ~8 useful slots/domain (sl 0..8 covers all 8 XCD
// residues), ~512 useful blocks (2/CU), 48KB LDS (3 blocks/CU cap), and the
// proven 2-phase stage-ahead schedule for in-block overlap.
// Per block: 64 perm-rows x (64 center + 64 domain) cols; A staged once.
__global__ __launch_bounds__(256) void gemm_l1_fused(
    const unsigned short* __restrict__ A,    // XCb [BATCH][KP1]
    const unsigned short* __restrict__ Wc,   // Wc1b [512][KP1]
    const unsigned short* __restrict__ Wd,   // Wd1b [D][512][KP1]
    const float* __restrict__ bc, const float* __restrict__ bd,
    unsigned short* __restrict__ Cc, unsigned short* __restrict__ Cd, // perm-space [BATCH][512]
    const int* __restrict__ starts, const int* __restrict__ perm) {
    __shared__ short As[2][64 * 64];    // 2 x 8KB
    __shared__ short Bs[2][128 * 64];   // 2 x 16KB  (rows 0-63 center, 64-127 domain)

    int xb = blockIdx.x;               // slot: 16 slots/domain (64 rows each)
    int d = xb >> 4, sl = xb & 15;
    int ds = starts[d], de = starts[d + 1];
    int m0 = ds + sl * 64;
    if (m0 >= de) return;
    int mEnd = de;
    int n0 = blockIdx.y * 64;          // column base within each chain's 512

    int tid = threadIdx.x;
    int w = tid >> 6, lane = tid & 63;
    int lr = lane & 15, q = lane >> 4;

    // ---- staging pointers (pre-swizzled global sources) ----
    const unsigned short* pA[2]; int sA[2];
    const unsigned short* pB[4]; int sB[4];
    #pragma unroll
    for (int i = 0; i < 2; i++) {
        int seg = i * 4 + w;               // [0,8)
        int ch = seg * 64 + lane;          // [0,512)
        int loc = ch >> 3, c = ch & 7;     // loc: A row 0..63
        int mm = m0 + loc; if (mm > mEnd - 1) mm = mEnd - 1;
        int rowp = perm[mm];
        pA[i] = A + (size_t)rowp * KP1 + ((c ^ (loc & 7)) << 3);
        sA[i] = seg * 512;
    }
    #pragma unroll
    for (int i = 0; i < 4; i++) {
        int seg = i * 4 + w;               // [0,16)
        int ch = seg * 64 + lane;          // [0,1024)
        int loc = ch >> 3, c = ch & 7;     // loc: B row 0..127
        const unsigned short* base = (loc < 64)
            ? (Wc + (size_t)(n0 + loc) * KP1)
            : (Wd + ((size_t)d * 512 + n0 + (loc - 64)) * KP1);
        pB[i] = base + ((c ^ (loc & 7)) << 3);
        sB[i] = seg * 512;
    }

    f32x4 acc[4][2];
    #pragma unroll
    for (int i = 0; i < 4; i++)
        #pragma unroll
        for (int j = 0; j < 2; j++)
            acc[i][j] = (f32x4){0.f, 0.f, 0.f, 0.f};

    // prologue: stage k-tile 0 into buffer 0
    #pragma unroll
    for (int i = 0; i < 2; i++) gload_lds16(pA[i], As[0] + sA[i]);
    #pragma unroll
    for (int i = 0; i < 4; i++) gload_lds16(pB[i], Bs[0] + sB[i]);
    __syncthreads();

    #pragma unroll 1
    for (int ks = 0; ks < KP1 / 64; ks++) {
        int cur = ks & 1, nxt = cur ^ 1;
        if (ks < KP1 / 64 - 1) {
            int k0 = (ks + 1) * 64;
            #pragma unroll
            for (int i = 0; i < 2; i++) gload_lds16(pA[i] + k0, As[nxt] + sA[i]);
            #pragma unroll
            for (int i = 0; i < 4; i++) gload_lds16(pB[i] + k0, Bs[nxt] + sB[i]);
        }
        #pragma unroll
        for (int half = 0; half < 2; half++) {
            int cc = half * 4 + q;
            bf16x8 af[4], bf[2];
            #pragma unroll
            for (int i = 0; i < 4; i++) {
                int m = i * 16 + lr;
                af[i] = *(const bf16x8*)(As[cur] + m * 64 + ((cc ^ (m & 7)) << 3));
            }
            #pragma unroll
            for (int j = 0; j < 2; j++) {
                int n = w * 32 + j * 16 + lr;   // B-lds row
                bf[j] = *(const bf16x8*)(Bs[cur] + n * 64 + ((cc ^ (n & 7)) << 3));
            }
            #pragma unroll
            for (int i = 0; i < 4; i++)
                #pragma unroll
                for (int j = 0; j < 2; j++)
                    acc[i][j] = __builtin_amdgcn_mfma_f32_16x16x32_bf16(
                        af[i], bf[j], acc[i][j], 0, 0, 0);
        }
        __syncthreads();   // buffer 'nxt' staged + visible for next iter
    }

    int chain = w >> 1, hn = w & 1;    // waves 0,1 -> center; 2,3 -> domain
    const float* bias = chain ? (bd + d * 512) : bc;
    unsigned short* C = chain ? Cd : Cc;
    #pragma unroll
    for (int i = 0; i < 4; i++) {
        #pragma unroll
        for (int j = 0; j < 2; j++) {
            int col = n0 + hn * 32 + j * 16 + lr;
            float bvv = bias[col];
            int rowb = m0 + i * 16 + q * 4;
            #pragma unroll
            for (int r = 0; r < 4; r++) {
                int row = rowb + r;
                if (row >= mEnd) continue;
                C[(size_t)row * 512 + col] = f2bf(fmaxf(acc[i][j][r] + bvv, 0.f));
            }
        }
    }
}

// ======== fused tail: L2 + L3 + STAR + final MLP + sigmoid, one kernel ========
// d = wgid%8 so XCD = d: one domain per XCD, W2[d]/W3[d] L2-resident.
__global__ __launch_bounds__(256) void tail_fused(
    const unsigned short* __restrict__ H1c, const unsigned short* __restrict__ H1d,
    const unsigned short* __restrict__ Wc2, const unsigned short* __restrict__ Wd2,
    const float* __restrict__ cb2v, const float* __restrict__ db2v,
    const unsigned short* __restrict__ Wc3, const unsigned short* __restrict__ Wd3,
    const float* __restrict__ cb3v, const float* __restrict__ db3v,
    const float* __restrict__ fW1, const float* __restrict__ fb1,
    const float* __restrict__ fW2, const float* __restrict__ fb2,
    const float* __restrict__ auxg, const int* __restrict__ perm,
    const int* __restrict__ starts, float* __restrict__ out) {

    __shared__ __align__(16) char smem[98304];
    short* Bsb[2] = { (short*)smem, (short*)(smem + 32768) };          // 2 x 32KB (B tiles)
    short* Asb[2] = { (short*)(smem + 65536), (short*)(smem + 69632) };// 2 x 4KB  (A tiles)
    short* H2    = (short*)(smem + 73728);                             // 16KB [32][256] swizzled
    short* fused = (short*)(smem + 90112);                             // 8KB  [32][128] swizzled

    int y = blockIdx.x;
    int d = y & 7, sl = y >> 3;        // XCD = wgid%8 = d
    int ds = starts[d], de = starts[d + 1];
    int m0 = ds + sl * 32;
    if (m0 >= de) return;
    int mEnd = de;

    int tid = threadIdx.x;
    int w = tid >> 6, lane = tid & 63;
    int lr = lane & 15, q = lane >> 4;

    // staging geometry: thread handles chunk ch = seg*64+lane; row = seg*8+(lane>>3)
    int bn = w * 8 + (lane >> 3);                 // base row (0..31) for seg=w
    int sw = ((lane & 7) ^ (bn & 7)) << 3;        // pre-swizzled chunk offset (shorts)
    int rowA = m0 + bn; if (rowA > mEnd - 1) rowA = mEnd - 1;

    const unsigned short* pA0  = H1c + (size_t)rowA * 512 + sw;
    const unsigned short* pA1  = H1d + (size_t)rowA * 512 + sw;
    const unsigned short* pW20 = Wc2 + (size_t)bn * 512 + sw;
    const unsigned short* pW21 = Wd2 + (size_t)d * 256 * 512 + (size_t)bn * 512 + sw;
    const unsigned short* pW30 = Wc3 + (size_t)bn * 256 + sw;
    const unsigned short* pW31 = Wd3 + (size_t)d * 128 * 256 + (size_t)bn * 256 + sw;

    auto stage_l2 = [&](int c, int k0, int pb) {
        const unsigned short* pa = c ? pA1 : pA0;
        const unsigned short* pw = c ? pW21 : pW20;
        gload_lds16(pa + k0, Asb[pb] + w * 512);
        #pragma unroll
        for (int i = 0; i < 8; i++)
            gload_lds16(pw + (size_t)i * 32 * 512 + k0, Bsb[pb] + (i * 4 + w) * 512);
    };
    auto stage_l3 = [&](int c, int k0, int pb) {
        const unsigned short* pw = c ? pW31 : pW30;
        #pragma unroll
        for (int i = 0; i < 4; i++)
            gload_lds16(pw + (size_t)i * 32 * 256 + k0, Bsb[pb] + (i * 4 + w) * 512);
    };

    // prologue: tile 0 (chain0 L2 k0=0)
    stage_l2(0, 0, 0);
    __syncthreads();

    #pragma unroll
    for (int c = 0; c < 2; c++) {
        // ---- L2: 32 x 256, K=512, 8 tiles ----
        f32x4 acc2[2][4];
        #pragma unroll
        for (int i = 0; i < 2; i++)
            #pragma unroll
            for (int j = 0; j < 4; j++) acc2[i][j] = (f32x4){0.f, 0.f, 0.f, 0.f};

        #pragma unroll
        for (int it = 0; it < 8; it++) {
            int t = c * 12 + it;
            int pb = t & 1, pn = pb ^ 1;
            if (it < 7) stage_l2(c, (it + 1) * 64, pn);
            else        stage_l3(c, 0, pn);

            #pragma unroll
            for (int half = 0; half < 2; half++) {
                int cc = half * 4 + q;
                bf16x8 af[2], bf[4];
                #pragma unroll
                for (int i = 0; i < 2; i++) {
                    int m = i * 16 + lr;
                    af[i] = *(const bf16x8*)(Asb[pb] + m * 64 + ((cc ^ (m & 7)) << 3));
                }
                #pragma unroll
                for (int j = 0; j < 4; j++) {
                    int n = w * 64 + j * 16 + lr;
                    bf[j] = *(const bf16x8*)(Bsb[pb] + n * 64 + ((cc ^ (n & 7)) << 3));
                }
                #pragma unroll
                for (int i = 0; i < 2; i++)
                    #pragma unroll
                    for (int j = 0; j < 4; j++)
                        acc2[i][j] = __builtin_amdgcn_mfma_f32_16x16x32_bf16(
                            af[i], bf[j], acc2[i][j], 0, 0, 0);
            }
            __syncthreads();
        }

        // L2 epilogue: bias + relu -> H2 LDS (swizzled for MFMA-A reads)
        const float* b2 = c ? (db2v + d * 256) : cb2v;
        #pragma unroll
        for (int i = 0; i < 2; i++)
            #pragma unroll
            for (int j = 0; j < 4; j++) {
                int col = w * 64 + j * 16 + lr;
                float bv = b2[col];
                int cch = col >> 3;
                #pragma unroll
                for (int r = 0; r < 4; r++) {
                    int row = i * 16 + q * 4 + r;
                    int pc = (cch & 24) | ((cch ^ (row & 7)) & 7);
                    float v = fmaxf(acc2[i][j][r] + bv, 0.f);
                    H2[row * 256 + pc * 8 + (col & 7)] = (short)f2bf(v);
                }
            }
        __syncthreads();

        // ---- L3: 32 x 128, K=256, 4 tiles; A = H2 (LDS) ----
        f32x4 acc3[2][2];
        #pragma unroll
        for (int i = 0; i < 2; i++)
            #pragma unroll
            for (int j = 0; j < 2; j++) acc3[i][j] = (f32x4){0.f, 0.f, 0.f, 0.f};

        #pragma unroll
        for (int it = 0; it < 4; it++) {
            int t = c * 12 + 8 + it;
            int pb = t & 1, pn = pb ^ 1;
            if (it < 3)      stage_l3(c, (it + 1) * 64, pn);
            else if (c == 0) stage_l2(1, 0, pn);

            #pragma unroll
            for (int half = 0; half < 2; half++) {
                int cc = half * 4 + q;
                int C = it * 8 + cc;   // global k-chunk in [0,32)
                bf16x8 af[2], bf[2];
                #pragma unroll
                for (int i = 0; i < 2; i++) {
                    int m = i * 16 + lr;
                    int pcm = (C & 24) | ((C ^ (m & 7)) & 7);
                    af[i] = *(const bf16x8*)(H2 + m * 256 + pcm * 8);
                }
                #pragma unroll
                for (int j = 0; j < 2; j++) {
                    int n = w * 32 + j * 16 + lr;
                    bf[j] = *(const bf16x8*)(Bsb[pb] + n * 64 + ((cc ^ (n & 7)) << 3));
                }
                #pragma unroll
                for (int i = 0; i < 2; i++)
                    #pragma unroll
                    for (int j = 0; j < 2; j++)
                        acc3[i][j] = __builtin_amdgcn_mfma_f32_16x16x32_bf16(
                            af[i], bf[j], acc3[i][j], 0, 0, 0);
            }
            __syncthreads();
        }

        // L3 epilogue -> fused (chain0: stash; chain1: STAR tanh-combine)
        const float* b3 = c ? (db3v + d * 128) : cb3v;
        #pragma unroll
        for (int i = 0; i < 2; i++)
            #pragma unroll
            for (int j = 0; j < 2; j++) {
                int col = w * 32 + j * 16 + lr;
                float bv = b3[col];
                int cch = col >> 3;
                #pragma unroll
                for (int r = 0; r < 4; r++) {
                    int row = i * 16 + q * 4 + r;
                    int pc = (cch & 8) | ((cch ^ (row & 7)) & 7);
                    int idx = row * 128 + pc * 8 + (col & 7);
                    if (c == 0) {
                        fused[idx] = (short)f2bf(acc3[i][j][r] + bv);
                    } else {
                        float cv = bf2f((unsigned short)fused[idx]);
                        fused[idx] = (short)f2bf(cv * tanhf(acc3[i][j][r] + bv));
                    }
                }
            }
        __syncthreads();
    }

    // ---- final MLP (R7-proven epilogue): (32x128)@(128x64) relu @ (64x1) + sigmoid ----
    short* Bsf = Bsb[0];
    float* Ls  = (float*)Asb[0];
    for (int s2 = tid; s2 < 1024; s2 += 256) {
        int n = s2 >> 4, cch = s2 & 15;
        bf16x8 vv;
        #pragma unroll
        for (int kk = 0; kk < 8; kk++)
            vv[kk] = (short)f2bf(fW1[(cch * 8 + kk) * 64 + n]);
        int pc = (cch & 8) | ((cch ^ (n & 7)) & 7);
        *(bf16x8*)(Bsf + n * 128 + pc * 8) = vv;
    }
    __syncthreads();

    int wm = w >> 1, wn = w & 1;
    f32x4 acc2f[2];
    #pragma unroll
    for (int j = 0; j < 2; j++) acc2f[j] = (f32x4){0.f, 0.f, 0.f, 0.f};
    #pragma unroll
    for (int g = 0; g < 4; g++) {
        int cc = g * 4 + q;
        int m = wm * 16 + lr;
        int pcm = (cc & 8) | ((cc ^ (m & 7)) & 7);
        bf16x8 af = *(const bf16x8*)(fused + m * 128 + pcm * 8);
        #pragma unroll
        for (int j = 0; j < 2; j++) {
            int n = wn * 32 + j * 16 + lr;
            int pcn = (cc & 8) | ((cc ^ (n & 7)) & 7);
            bf16x8 bf = *(const bf16x8*)(Bsf + n * 128 + pcn * 8);
            acc2f[j] = __builtin_amdgcn_mfma_f32_16x16x32_bf16(af, bf, acc2f[j], 0, 0, 0);
        }
    }

    float w2v[2], b1v[2];
    #pragma unroll
    for (int j = 0; j < 2; j++) {
        int col = wn * 32 + j * 16 + lr;
        w2v[j] = fW2[col];
        b1v[j] = fb1[col];
    }
    float rowv[4];
    #pragma unroll
    for (int r = 0; r < 4; r++) {
        float v = 0.f;
        #pragma unroll
        for (int j = 0; j < 2; j++)
            v += fmaxf(acc2f[j][r] + b1v[j], 0.f) * w2v[j];
        v += __shfl_xor(v, 1);
        v += __shfl_xor(v, 2);
        v += __shfl_xor(v, 4);
        v += __shfl_xor(v, 8);
        rowv[r] = v;
    }
    if (wn == 0 && lr == 0) {
        #pragma unroll
        for (int r = 0; r < 4; r++)
            Ls[wm * 16 + q * 4 + r] = rowv[r];
    }
    __syncthreads();
    if (wn == 1 && lr == 0) {
        float b2 = fb2[0];
        #pragma unroll
        for (int r = 0; r < 4; r++) {
            int row = wm * 16 + q * 4 + r;
            int p = m0 + row;
            if (p < mEnd) {
                int orow = perm[p];
                float logit = Ls[row] + rowv[r] + b2 + auxg[orow];
                out[orow] = 1.f / (1.f + expf(-logit));
            }
        }
    }
}

extern "C" void kernel_launch(void* const* d_in, const int* in_sizes, int n_in,
                              void* d_out, int out_size, void* d_ws, size_t ws_size,
                              hipStream_t stream) {
    (void)in_sizes; (void)n_in; (void)out_size; (void)ws_size;

    const float* x    = (const float*)d_in[0];
    const int*   dom  = (const int*)  d_in[1];
    const float* pnw  = (const float*)d_in[2];
    const float* pnb  = (const float*)d_in[3];
    const float* demb = (const float*)d_in[4];
    const float* crw  = (const float*)d_in[5];
    const float* crb  = (const float*)d_in[6];
    const float* cW1  = (const float*)d_in[7];
    const float* cb1  = (const float*)d_in[8];
    const float* cW2  = (const float*)d_in[9];
    const float* cb2  = (const float*)d_in[10];
    const float* cW3  = (const float*)d_in[11];
    const float* cb3  = (const float*)d_in[12];
    const float* dW1  = (const float*)d_in[13];
    const float* db1  = (const float*)d_in[14];
    const float* dW2  = (const float*)d_in[15];
    const float* db2  = (const float*)d_in[16];
    const float* dW3  = (const float*)d_in[17];
    const float* db3  = (const float*)d_in[18];
    const float* fW1  = (const float*)d_in[19];
    const float* fb1  = (const float*)d_in[20];
    const float* fW2  = (const float*)d_in[21];
    const float* fb2  = (const float*)d_in[22];
    const float* aW1  = (const float*)d_in[23];
    const float* ab1  = (const float*)d_in[24];
    const float* aW2  = (const float*)d_in[25];
    const float* ab2  = (const float*)d_in[26];
    float* out = (float*)d_out;

    char* base = (char*)d_ws;
    size_t o = 0;
    auto alloc = [&](size_t bytes) { char* p = base + o; o += (bytes + 255) & ~size_t(255); return p; };

    int* perm   = (int*)alloc(BATCH * 4);
    int* starts = (int*)alloc((NDOM + 1) * 4);
    float* auxg = (float*)alloc(BATCH * 4);
    unsigned short* XCb  = (unsigned short*)alloc((size_t)BATCH * KP1 * 2);
    unsigned short* H1c  = (unsigned short*)alloc((size_t)BATCH * 512 * 2);
    unsigned short* H1d  = (unsigned short*)alloc((size_t)BATCH * 512 * 2);
    unsigned short* Wc1b = (unsigned short*)alloc((size_t)512 * KP1 * 2);
    unsigned short* Wd1b = (unsigned short*)alloc((size_t)NDOM * 512 * KP1 * 2);
    unsigned short* Wc2b = (unsigned short*)alloc((size_t)256 * 512 * 2);
    unsigned short* Wd2b = (unsigned short*)alloc((size_t)NDOM * 256 * 512 * 2);
    unsigned short* Wc3b = (unsigned short*)alloc((size_t)128 * 256 * 2);
    unsigned short* Wd3b = (unsigned short*)alloc((size_t)NDOM * 128 * 256 * 2);

    // 1) convert + grouping + prep (one launch)
    front<<<NCONV + 1 + BATCH / 4, 256, 0, stream>>>(
        dom, perm, starts, cW1, dW1, cW2, dW2, cW3, dW3,
        Wc1b, Wd1b, Wc2b, Wd2b, Wc3b, Wd3b,
        x, pnw, pnb, demb, crw, crb, aW1, ab1, aW2, ab2, XCb, auxg);

    // 2) L1 chain-fused, 64-row slots (16/domain), double-buffered:
    //    useful slots span all 8 XCD residues; ~512 useful blocks (2/CU)
    gemm_l1_fused<<<dim3(NDOM * 16, 8), 256, 0, stream>>>(
        XCb, Wc1b, Wd1b, cb1, db1, H1c, H1d, starts, perm);

    // 3) fused tail: L2 + L3 + STAR + final MLP + sigmoid (32-row slots),
    //    d = wgid%8 so one domain's weights stay in one XCD's L2
    tail_fused<<<NDOM * 128, 256, 0, stream>>>(
        H1c, H1d, Wc2b, Wd2b, cb2, db2, Wc3b, Wd3b, cb3, db3,
        fW1, fb1, fW2, fb2, auxg, perm, starts, out);
}

// Round 7
// 193.722 us; speedup vs baseline: 1.3467x; 1.0215x over previous
//
#include <hip/hip_runtime.h>
#include <math.h>
#include <stdint.h>

#define BATCH 4096
#define FEAT  1024
#define EDIM  16
#define NDOM  8
#define TDIM  1040   // FEAT + EDIM
#define KP1   1088   // TDIM padded to multiple of 64
#define NLAYER 3
#define EPSV  1e-5f

typedef __attribute__((ext_vector_type(8))) short bf16x8;
typedef __attribute__((ext_vector_type(4))) float f32x4;

// s_waitcnt with ONLY vmcnt=N (lgkm/exp unconstrained). gfx9 encoding:
// vmcnt[3:0]=simm[3:0], vmcnt[5:4]=simm[15:14], expcnt=simm[6:4], lgkm=simm[11:8]
#define VMW(N)  __builtin_amdgcn_s_waitcnt((((N)&15)|(((N)>>4)<<14)|(15<<8)|(7<<4)))
// lgkmcnt(0) only (vmcnt=63 i.e. unconstrained, expcnt=7)
#define LGKW0   __builtin_amdgcn_s_waitcnt((15|(3<<14)|(7<<4)))
#define SBAR    __builtin_amdgcn_s_barrier()
#define SCB     __builtin_amdgcn_sched_barrier(0)

__device__ __forceinline__ unsigned short f2bf(float f) {
    union { float f; unsigned int u; } v; v.f = f;
    unsigned int u = v.u;
    return (unsigned short)((u + 0x7fffu + ((u >> 16) & 1u)) >> 16);
}
__device__ __forceinline__ float bf2f(unsigned short u) {
    union { unsigned int u; float f; } v; v.u = ((unsigned int)u) << 16; return v.f;
}
__device__ __forceinline__ void gload_lds16(const void* g, void* l) {
    __builtin_amdgcn_global_load_lds(
        (const __attribute__((address_space(1))) void*)(g),
        (__attribute__((address_space(3))) void*)(l), 16, 0, 0);
}

// 64x64 convert tiles
#define T_W1 136
#define T_W2 32
#define T_W3 8
#define NCONV (T_W1*9 + T_W2*9 + T_W3*9)   // 1584

// ======== kernel 1 "front": converts + grouping + prep (R11-proven) ========
__global__ __launch_bounds__(256) void front(
    const int* __restrict__ dom, int* __restrict__ perm, int* __restrict__ starts,
    const float* __restrict__ cW1, const float* __restrict__ dW1,
    const float* __restrict__ cW2, const float* __restrict__ dW2,
    const float* __restrict__ cW3, const float* __restrict__ dW3,
    unsigned short* __restrict__ Wc1b, unsigned short* __restrict__ Wd1b,
    unsigned short* __restrict__ Wc2b, unsigned short* __restrict__ Wd2b,
    unsigned short* __restrict__ Wc3b, unsigned short* __restrict__ Wd3b,
    const float* __restrict__ x,
    const float* __restrict__ pnw, const float* __restrict__ pnb,
    const float* __restrict__ demb,
    const float* __restrict__ crw, const float* __restrict__ crb,
    const float* __restrict__ aW1, const float* __restrict__ ab1,
    const float* __restrict__ aW2, const float* __restrict__ ab2,
    unsigned short* __restrict__ XCb, float* __restrict__ auxg) {
    int b = blockIdx.x;
    int t = threadIdx.x;

    if (b < NCONV) {
        __shared__ float tile[64][65];
        const float* src; unsigned short* dst; int K, N, Kp, rr;
        if (b < T_W1)            { src = cW1; dst = Wc1b; K = TDIM; N = 512; Kp = KP1; rr = b; }
        else if (b < T_W1*9)     { int r = b - T_W1; int z = r / T_W1; rr = r % T_W1;
                                   src = dW1 + (size_t)z * TDIM * 512; dst = Wd1b + (size_t)z * 512 * KP1;
                                   K = TDIM; N = 512; Kp = KP1; }
        else if (b < T_W1*9+T_W2)   { src = cW2; dst = Wc2b; K = 512; N = 256; Kp = 512; rr = b - T_W1*9; }
        else if (b < T_W1*9+T_W2*9) { int r = b - (T_W1*9+T_W2); int z = r / T_W2; rr = r % T_W2;
                                   src = dW2 + (size_t)z * 512 * 256; dst = Wd2b + (size_t)z * 256 * 512;
                                   K = 512; N = 256; Kp = 512; }
        else if (b < T_W1*9+T_W2*9+T_W3) { src = cW3; dst = Wc3b; K = 256; N = 128; Kp = 256; rr = b - (T_W1*9+T_W2*9); }
        else                     { int r = b - (T_W1*9+T_W2*9+T_W3); int z = r / T_W3; rr = r % T_W3;
                                   src = dW3 + (size_t)z * 256 * 128; dst = Wd3b + (size_t)z * 128 * 256;
                                   K = 256; N = 128; Kp = 256; }
        int kt = Kp >> 6;
        int kb = rr % kt, nb = rr / kt;
        int k0 = kb * 64, n0 = nb * 64;
        #pragma unroll
        for (int i = 0; i < 4; i++) {
            int flat = t + i * 256;
            int kr = flat >> 4, c4 = flat & 15;
            int k = k0 + kr;
            float4 v = make_float4(0.f, 0.f, 0.f, 0.f);
            if (k < K) v = *(const float4*)(src + (size_t)k * N + n0 + c4 * 4);
            tile[kr][c4 * 4 + 0] = v.x;
            tile[kr][c4 * 4 + 1] = v.y;
            tile[kr][c4 * 4 + 2] = v.z;
            tile[kr][c4 * 4 + 3] = v.w;
        }
        __syncthreads();
        #pragma unroll
        for (int i = 0; i < 4; i++) {
            int flat = t + i * 256;
            int n = flat >> 4, kg = flat & 15;
            ushort4 sv;
            sv.x = f2bf(tile[kg * 4 + 0][n]);
            sv.y = f2bf(tile[kg * 4 + 1][n]);
            sv.z = f2bf(tile[kg * 4 + 2][n]);
            sv.w = f2bf(tile[kg * 4 + 3][n]);
            *(ushort4*)(dst + (size_t)(n0 + n) * Kp + k0 + kg * 4) = sv;
        }
        return;
    }
    if (b == NCONV) {
        __shared__ int cnt[NDOM];
        __shared__ int off[NDOM];
        if (t < NDOM) cnt[t] = 0;
        __syncthreads();
        for (int i = t; i < BATCH; i += 256) atomicAdd(&cnt[dom[i]], 1);
        __syncthreads();
        if (t == 0) {
            int s = 0;
            for (int d = 0; d < NDOM; d++) { off[d] = s; starts[d] = s; s += cnt[d]; }
            starts[NDOM] = s;
        }
        __syncthreads();
        for (int i = t; i < BATCH; i += 256) {
            int p = atomicAdd(&off[dom[i]], 1);
            perm[p] = i;
        }
        return;
    }

    // ---- prep: one wave per row, row in registers, barrier-free ----
    int w = t >> 6, lane = t & 63;
    int row = (b - NCONV - 1) * 4 + w;
    int d = dom[row];

    float4 X[4];
    #pragma unroll
    for (int j = 0; j < 4; j++)
        X[j] = *(const float4*)(x + (size_t)row * FEAT + 4 * lane + 256 * j);

    float s = 0.f, ss = 0.f;
    #pragma unroll
    for (int j = 0; j < 4; j++) {
        s  += X[j].x + X[j].y + X[j].z + X[j].w;
        ss += X[j].x*X[j].x + X[j].y*X[j].y + X[j].z*X[j].z + X[j].w*X[j].w;
    }
    #pragma unroll
    for (int m = 1; m < 64; m <<= 1) {
        s  += __shfl_xor(s,  m);
        ss += __shfl_xor(ss, m);
    }
    float mean = s / (float)FEAT;
    float var  = ss / (float)FEAT - mean * mean;
    float rstd = rsqrtf(var + EPSV);

    float4 x0[4], xc[4];
    #pragma unroll
    for (int j = 0; j < 4; j++) {
        float4 wv = *(const float4*)(pnw + (size_t)d * FEAT + 4 * lane + 256 * j);
        float4 bv = *(const float4*)(pnb + (size_t)d * FEAT + 4 * lane + 256 * j);
        x0[j].x = (X[j].x - mean) * rstd * wv.x + bv.x;
        x0[j].y = (X[j].y - mean) * rstd * wv.y + bv.y;
        x0[j].z = (X[j].z - mean) * rstd * wv.z + bv.z;
        x0[j].w = (X[j].w - mean) * rstd * wv.w + bv.w;
        xc[j] = x0[j];
    }
    float x0e = 0.f, xce = 0.f;
    if (lane < EDIM) { x0e = demb[d * EDIM + lane]; xce = x0e; }

    #pragma unroll
    for (int l = 0; l < NLAYER; l++) {
        const float* wl = crw + l * TDIM;
        const float* bl = crb + l * TDIM;
        float partial = 0.f;
        #pragma unroll
        for (int j = 0; j < 4; j++) {
            float4 wv = *(const float4*)(wl + 4 * lane + 256 * j);
            partial += xc[j].x*wv.x + xc[j].y*wv.y + xc[j].z*wv.z + xc[j].w*wv.w;
        }
        if (lane < EDIM) partial += xce * wl[FEAT + lane];
        #pragma unroll
        for (int m = 1; m < 64; m <<= 1) partial += __shfl_xor(partial, m);
        float proj = partial;
        #pragma unroll
        for (int j = 0; j < 4; j++) {
            float4 bv = *(const float4*)(bl + 4 * lane + 256 * j);
            xc[j].x = fmaf(x0[j].x, proj, bv.x + xc[j].x);
            xc[j].y = fmaf(x0[j].y, proj, bv.y + xc[j].y);
            xc[j].z = fmaf(x0[j].z, proj, bv.z + xc[j].z);
            xc[j].w = fmaf(x0[j].w, proj, bv.w + xc[j].w);
        }
        if (lane < EDIM) xce = fmaf(x0e, proj, bl[FEAT + lane] + xce);
    }

    #pragma unroll
    for (int j = 0; j < 4; j++) {
        ushort4 sv;
        sv.x = f2bf(xc[j].x); sv.y = f2bf(xc[j].y);
        sv.z = f2bf(xc[j].z); sv.w = f2bf(xc[j].w);
        *(ushort4*)(XCb + (size_t)row * KP1 + 4 * lane + 256 * j) = sv;
    }
    XCb[(size_t)row * KP1 + FEAT + lane] = (lane < EDIM) ? f2bf(xce) : 0;

    float h = (lane < 32) ? ab1[lane] : 0.f;
    #pragma unroll
    for (int e = 0; e < EDIM; e++) {
        float ev = __shfl(xce, e);
        if (lane < 32) h = fmaf(ev, aW1[e * 32 + lane], h);
    }
    float c = (lane < 32) ? fmaxf(h, 0.f) * aW2[lane] : 0.f;
    #pragma unroll
    for (int m = 1; m < 64; m <<= 1) c += __shfl_xor(c, m);
    if (lane == 0) auxg[row] = c + ab2[0];
}

// ======== L1 GEMM, chain-fused, 64m x 128n, TRUE pipeline (counted vmcnt) ========
// Issue next stage, wait vmcnt(6) (= the 6 in-flight loads of the NEXT
// stage), raw barrier, compute, lgkmcnt(0), raw barrier. Prefetch survives
// across barriers (catalog T4).
__global__ __launch_bounds__(256) void gemm_l1_fused(
    const unsigned short* __restrict__ A,    // XCb [BATCH][KP1]
    const unsigned short* __restrict__ Wc,   // Wc1b [512][KP1]
    const unsigned short* __restrict__ Wd,   // Wd1b [D][512][KP1]
    const float* __restrict__ bc, const float* __restrict__ bd,
    unsigned short* __restrict__ Cc, unsigned short* __restrict__ Cd, // perm-space [BATCH][512]
    const int* __restrict__ starts, const int* __restrict__ perm) {
    __shared__ short As[2][64 * 64];    // 2 x 8KB
    __shared__ short Bs[2][128 * 64];   // 2 x 16KB

    int xb = blockIdx.x;               // slot: 16 slots/domain (64 rows each)
    int d = xb >> 4, sl = xb & 15;
    int ds = starts[d], de = starts[d + 1];
    int m0 = ds + sl * 64;
    if (m0 >= de) return;
    int mEnd = de;
    int n0 = blockIdx.y * 64;          // column base within each chain's 512

    int tid = threadIdx.x;
    int w = tid >> 6, lane = tid & 63;
    int lr = lane & 15, q = lane >> 4;

    const unsigned short* pA[2]; int sA[2];
    const unsigned short* pB[4]; int sB[4];
    #pragma unroll
    for (int i = 0; i < 2; i++) {
        int seg = i * 4 + w;
        int ch = seg * 64 + lane;
        int loc = ch >> 3, c = ch & 7;
        int mm = m0 + loc; if (mm > mEnd - 1) mm = mEnd - 1;
        int rowp = perm[mm];
        pA[i] = A + (size_t)rowp * KP1 + ((c ^ (loc & 7)) << 3);
        sA[i] = seg * 512;
    }
    #pragma unroll
    for (int i = 0; i < 4; i++) {
        int seg = i * 4 + w;
        int ch = seg * 64 + lane;
        int loc = ch >> 3, c = ch & 7;
        const unsigned short* base = (loc < 64)
            ? (Wc + (size_t)(n0 + loc) * KP1)
            : (Wd + ((size_t)d * 512 + n0 + (loc - 64)) * KP1);
        pB[i] = base + ((c ^ (loc & 7)) << 3);
        sB[i] = seg * 512;
    }

    f32x4 acc[4][2];
    #pragma unroll
    for (int i = 0; i < 4; i++)
        #pragma unroll
        for (int j = 0; j < 2; j++)
            acc[i][j] = (f32x4){0.f, 0.f, 0.f, 0.f};

    // prologue: stage k-tile 0 into buffer 0 (6 loads/wave in flight)
    #pragma unroll
    for (int i = 0; i < 2; i++) gload_lds16(pA[i], As[0] + sA[i]);
    #pragma unroll
    for (int i = 0; i < 4; i++) gload_lds16(pB[i], Bs[0] + sB[i]);

    #pragma unroll 1
    for (int ks = 0; ks < KP1 / 64; ks++) {
        int cur = ks & 1, nxt = cur ^ 1;
        if (ks < KP1 / 64 - 1) {
            int k0 = (ks + 1) * 64;
            #pragma unroll
            for (int i = 0; i < 2; i++) gload_lds16(pA[i] + k0, As[nxt] + sA[i]);
            #pragma unroll
            for (int i = 0; i < 4; i++) gload_lds16(pB[i] + k0, Bs[nxt] + sB[i]);
            VMW(6);               // wait tile ks only; ks+1 stays in flight
        } else {
            VMW(0);
        }
        SBAR; SCB;
        #pragma unroll
        for (int half = 0; half < 2; half++) {
            int cc = half * 4 + q;
            bf16x8 af[4], bf[2];
            #pragma unroll
            for (int i = 0; i < 4; i++) {
                int m = i * 16 + lr;
                af[i] = *(const bf16x8*)(As[cur] + m * 64 + ((cc ^ (m & 7)) << 3));
            }
            #pragma unroll
            for (int j = 0; j < 2; j++) {
                int n = w * 32 + j * 16 + lr;
                bf[j] = *(const bf16x8*)(Bs[cur] + n * 64 + ((cc ^ (n & 7)) << 3));
            }
            #pragma unroll
            for (int i = 0; i < 4; i++)
                #pragma unroll
                for (int j = 0; j < 2; j++)
                    acc[i][j] = __builtin_amdgcn_mfma_f32_16x16x32_bf16(
                        af[i], bf[j], acc[i][j], 0, 0, 0);
        }
        LGKW0; SBAR; SCB;         // all waves done reading 'cur' -> reusable
    }

    int chain = w >> 1, hn = w & 1;    // waves 0,1 -> center; 2,3 -> domain
    const float* bias = chain ? (bd + d * 512) : bc;
    unsigned short* C = chain ? Cd : Cc;
    #pragma unroll
    for (int i = 0; i < 4; i++) {
        #pragma unroll
        for (int j = 0; j < 2; j++) {
            int col = n0 + hn * 32 + j * 16 + lr;
            float bvv = bias[col];
            int rowb = m0 + i * 16 + q * 4;
            #pragma unroll
            for (int r = 0; r < 4; r++) {
                int row = rowb + r;
                if (row >= mEnd) continue;
                C[(size_t)row * 512 + col] = f2bf(fmaxf(acc[i][j][r] + bvv, 0.f));
            }
        }
    }
}

// ======== fused tail: L2+L3+STAR+final MLP+sigmoid, depth-2 counted pipeline ====
// 24 flat stages (2 chains x (8 L2 + 4 L3)); 2 x 36KB stage buffers (96KB
// LDS total — session-proven footprint); counted vmcnt keeps 1 stage in
// flight across barriers. d-decode = R3 (measured faster than d=wgid%8).
__global__ __launch_bounds__(256) void tail_fused(
    const unsigned short* __restrict__ H1c, const unsigned short* __restrict__ H1d,
    const unsigned short* __restrict__ Wc2, const unsigned short* __restrict__ Wd2,
    const float* __restrict__ cb2v, const float* __restrict__ db2v,
    const unsigned short* __restrict__ Wc3, const unsigned short* __restrict__ Wd3,
    const float* __restrict__ cb3v, const float* __restrict__ db3v,
    const float* __restrict__ fW1, const float* __restrict__ fb1,
    const float* __restrict__ fW2, const float* __restrict__ fb2,
    const float* __restrict__ auxg, const int* __restrict__ perm,
    const int* __restrict__ starts, float* __restrict__ out) {

    __shared__ __align__(16) char smem[98304];   // 96KB (proven)
    short* BufB[2]; short* BufA[2];
    #pragma unroll
    for (int i = 0; i < 2; i++) {
        BufB[i] = (short*)(smem + i * 36864);            // 32KB B tile
        BufA[i] = (short*)(smem + i * 36864 + 32768);    // 4KB  A tile
    }
    short* H2    = (short*)(smem + 73728);               // 16KB [32][256] swizzled
    short* fused = (short*)(smem + 90112);               // 8KB  [32][128] swizzled

    int y = blockIdx.x;
    int d = y >> 7, sl = y & 127;      // R3 decode (measured faster)
    int ds = starts[d], de = starts[d + 1];
    int m0 = ds + sl * 32;
    if (m0 >= de) return;
    int mEnd = de;

    int tid = threadIdx.x;
    int w = tid >> 6, lane = tid & 63;
    int lr = lane & 15, q = lane >> 4;

    int bn = w * 8 + (lane >> 3);
    int sw = ((lane & 7) ^ (bn & 7)) << 3;
    int rowA = m0 + bn; if (rowA > mEnd - 1) rowA = mEnd - 1;

    const unsigned short* pA0  = H1c + (size_t)rowA * 512 + sw;
    const unsigned short* pA1  = H1d + (size_t)rowA * 512 + sw;
    const unsigned short* pW20 = Wc2 + (size_t)bn * 512 + sw;
    const unsigned short* pW21 = Wd2 + (size_t)d * 256 * 512 + (size_t)bn * 512 + sw;
    const unsigned short* pW30 = Wc3 + (size_t)bn * 256 + sw;
    const unsigned short* pW31 = Wd3 + (size_t)d * 128 * 256 + (size_t)bn * 256 + sw;

    // stage s (0..23): c=s/12, k=s%12. k<8: L2 (9 loads/wave), else L3 (4).
    auto istep = [&](int s) {
        int c = s / 12, k = s % 12, b = s & 1;
        if (k < 8) {
            const unsigned short* pa = c ? pA1 : pA0;
            const unsigned short* pw = c ? pW21 : pW20;
            int k0 = k * 64;
            gload_lds16(pa + k0, BufA[b] + w * 512);
            #pragma unroll
            for (int i = 0; i < 8; i++)
                gload_lds16(pw + (size_t)i * 32 * 512 + k0, BufB[b] + (i * 4 + w) * 512);
        } else {
            const unsigned short* pw = c ? pW31 : pW30;
            int k0 = (k - 8) * 64;
            #pragma unroll
            for (int i = 0; i < 4; i++)
                gload_lds16(pw + (size_t)i * 32 * 256 + k0, BufB[b] + (i * 4 + w) * 512);
        }
    };

    f32x4 acc2[2][4], acc3[2][2];

    auto cstep = [&](int s) {
        int c = s / 12, k = s % 12, b = s & 1;
        if (k < 8) {
            if (k == 0) {
                #pragma unroll
                for (int i = 0; i < 2; i++)
                    #pragma unroll
                    for (int j = 0; j < 4; j++) acc2[i][j] = (f32x4){0.f, 0.f, 0.f, 0.f};
            }
            #pragma unroll
            for (int half = 0; half < 2; half++) {
                int cc = half * 4 + q;
                bf16x8 af[2], bf[4];
                #pragma unroll
                for (int i = 0; i < 2; i++) {
                    int m = i * 16 + lr;
                    af[i] = *(const bf16x8*)(BufA[b] + m * 64 + ((cc ^ (m & 7)) << 3));
                }
                #pragma unroll
                for (int j = 0; j < 4; j++) {
                    int n = w * 64 + j * 16 + lr;
                    bf[j] = *(const bf16x8*)(BufB[b] + n * 64 + ((cc ^ (n & 7)) << 3));
                }
                #pragma unroll
                for (int i = 0; i < 2; i++)
                    #pragma unroll
                    for (int j = 0; j < 4; j++)
                        acc2[i][j] = __builtin_amdgcn_mfma_f32_16x16x32_bf16(
                            af[i], bf[j], acc2[i][j], 0, 0, 0);
            }
            if (k == 7) {   // L2 epilogue -> H2 (swizzled)
                const float* b2 = c ? (db2v + d * 256) : cb2v;
                #pragma unroll
                for (int i = 0; i < 2; i++)
                    #pragma unroll
                    for (int j = 0; j < 4; j++) {
                        int col = w * 64 + j * 16 + lr;
                        float bv = b2[col];
                        int cch = col >> 3;
                        #pragma unroll
                        for (int r = 0; r < 4; r++) {
                            int row = i * 16 + q * 4 + r;
                            int pc = (cch & 24) | ((cch ^ (row & 7)) & 7);
                            float v = fmaxf(acc2[i][j][r] + bv, 0.f);
                            H2[row * 256 + pc * 8 + (col & 7)] = (short)f2bf(v);
                        }
                    }
            }
        } else {
            int it = k - 8;
            if (it == 0) {
                #pragma unroll
                for (int i = 0; i < 2; i++)
                    #pragma unroll
                    for (int j = 0; j < 2; j++) acc3[i][j] = (f32x4){0.f, 0.f, 0.f, 0.f};
            }
            #pragma unroll
            for (int half = 0; half < 2; half++) {
                int cc = half * 4 + q;
                int C = it * 8 + cc;
                bf16x8 af[2], bf[2];
                #pragma unroll
                for (int i = 0; i < 2; i++) {
                    int m = i * 16 + lr;
                    int pcm = (C & 24) | ((C ^ (m & 7)) & 7);
                    af[i] = *(const bf16x8*)(H2 + m * 256 + pcm * 8);
                }
                #pragma unroll
                for (int j = 0; j < 2; j++) {
                    int n = w * 32 + j * 16 + lr;
                    bf[j] = *(const bf16x8*)(BufB[b] + n * 64 + ((cc ^ (n & 7)) << 3));
                }
                #pragma unroll
                for (int i = 0; i < 2; i++)
                    #pragma unroll
                    for (int j = 0; j < 2; j++)
                        acc3[i][j] = __builtin_amdgcn_mfma_f32_16x16x32_bf16(
                            af[i], bf[j], acc3[i][j], 0, 0, 0);
            }
            if (it == 3) {   // L3 epilogue -> fused
                const float* b3 = c ? (db3v + d * 128) : cb3v;
                #pragma unroll
                for (int i = 0; i < 2; i++)
                    #pragma unroll
                    for (int j = 0; j < 2; j++) {
                        int col = w * 32 + j * 16 + lr;
                        float bv = b3[col];
                        int cch = col >> 3;
                        #pragma unroll
                        for (int r = 0; r < 4; r++) {
                            int row = i * 16 + q * 4 + r;
                            int pc = (cch & 8) | ((cch ^ (row & 7)) & 7);
                            int idx = row * 128 + pc * 8 + (col & 7);
                            if (c == 0) {
                                fused[idx] = (short)f2bf(acc3[i][j][r] + bv);
                            } else {
                                float cv = bf2f((unsigned short)fused[idx]);
                                fused[idx] = (short)f2bf(cv * tanhf(acc3[i][j][r] + bv));
                            }
                        }
                    }
            }
        }
    };

    // TSTEP(S,N): N = loads(S+1) — stage S+1 stays in flight across barriers.
    #define TSTEP(S, NW) do { \
        VMW(NW); SBAR; SCB; \
        cstep(S); \
        LGKW0; SBAR; SCB; \
        if ((S) + 2 < 24) istep((S) + 2); \
    } while (0)

    // prologue: stages 0,1 in flight
    istep(0); istep(1);

    TSTEP(0, 9);   TSTEP(1, 9);   TSTEP(2, 9);   TSTEP(3, 9);
    TSTEP(4, 9);   TSTEP(5, 9);   TSTEP(6, 9);   TSTEP(7, 4);
    TSTEP(8, 4);   TSTEP(9, 4);   TSTEP(10, 4);  TSTEP(11, 9);
    TSTEP(12, 9);  TSTEP(13, 9);  TSTEP(14, 9);  TSTEP(15, 9);
    TSTEP(16, 9);  TSTEP(17, 9);  TSTEP(18, 9);  TSTEP(19, 4);
    TSTEP(20, 4);  TSTEP(21, 4);  TSTEP(22, 4);  TSTEP(23, 0);
    #undef TSTEP

    __syncthreads();   // vmcnt already 0; full fence before buffer reuse

    // ---- final MLP (R7-proven epilogue): (32x128)@(128x64) relu @ (64x1) + sigmoid ----
    short* Bsf = BufB[0];
    float* Ls  = (float*)BufA[0];
    for (int s2 = tid; s2 < 1024; s2 += 256) {
        int n = s2 >> 4, cch = s2 & 15;
        bf16x8 vv;
        #pragma unroll
        for (int kk = 0; kk < 8; kk++)
            vv[kk] = (short)f2bf(fW1[(cch * 8 + kk) * 64 + n]);
        int pc = (cch & 8) | ((cch ^ (n & 7)) & 7);
        *(bf16x8*)(Bsf + n * 128 + pc * 8) = vv;
    }
    __syncthreads();

    int wm = w >> 1, wn = w & 1;
    f32x4 acc2f[2];
    #pragma unroll
    for (int j = 0; j < 2; j++) acc2f[j] = (f32x4){0.f, 0.f, 0.f, 0.f};
    #pragma unroll
    for (int g = 0; g < 4; g++) {
        int cc = g * 4 + q;
        int m = wm * 16 + lr;
        int pcm = (cc & 8) | ((cc ^ (m & 7)) & 7);
        bf16x8 af = *(const bf16x8*)(fused + m * 128 + pcm * 8);
        #pragma unroll
        for (int j = 0; j < 2; j++) {
            int n = wn * 32 + j * 16 + lr;
            int pcn = (cc & 8) | ((cc ^ (n & 7)) & 7);
            bf16x8 bf = *(const bf16x8*)(Bsf + n * 128 + pcn * 8);
            acc2f[j] = __builtin_amdgcn_mfma_f32_16x16x32_bf16(af, bf, acc2f[j], 0, 0, 0);
        }
    }

    float w2v[2], b1v[2];
    #pragma unroll
    for (int j = 0; j < 2; j++) {
        int col = wn * 32 + j * 16 + lr;
        w2v[j] = fW2[col];
        b1v[j] = fb1[col];
    }
    float rowv[4];
    #pragma unroll
    for (int r = 0; r < 4; r++) {
        float v = 0.f;
        #pragma unroll
        for (int j = 0; j < 2; j++)
            v += fmaxf(acc2f[j][r] + b1v[j], 0.f) * w2v[j];
        v += __shfl_xor(v, 1);
        v += __shfl_xor(v, 2);
        v += __shfl_xor(v, 4);
        v += __shfl_xor(v, 8);
        rowv[r] = v;
    }
    if (wn == 0 && lr == 0) {
        #pragma unroll
        for (int r = 0; r < 4; r++)
            Ls[wm * 16 + q * 4 + r] = rowv[r];
    }
    __syncthreads();
    if (wn == 1 && lr == 0) {
        float b2 = fb2[0];
        #pragma unroll
        for (int r = 0; r < 4; r++) {
            int row = wm * 16 + q * 4 + r;
            int p = m0 + row;
            if (p < mEnd) {
                int orow = perm[p];
                float logit = Ls[row] + rowv[r] + b2 + auxg[orow];
                out[orow] = 1.f / (1.f + expf(-logit));
            }
        }
    }
}

extern "C" void kernel_launch(void* const* d_in, const int* in_sizes, int n_in,
                              void* d_out, int out_size, void* d_ws, size_t ws_size,
                              hipStream_t stream) {
    (void)in_sizes; (void)n_in; (void)out_size; (void)ws_size;

    const float* x    = (const float*)d_in[0];
    const int*   dom  = (const int*)  d_in[1];
    const float* pnw  = (const float*)d_in[2];
    const float* pnb  = (const float*)d_in[3];
    const float* demb = (const float*)d_in[4];
    const float* crw  = (const float*)d_in[5];
    const float* crb  = (const float*)d_in[6];
    const float* cW1  = (const float*)d_in[7];
    const float* cb1  = (const float*)d_in[8];
    const float* cW2  = (const float*)d_in[9];
    const float* cb2  = (const float*)d_in[10];
    const float* cW3  = (const float*)d_in[11];
    const float* cb3  = (const float*)d_in[12];
    const float* dW1  = (const float*)d_in[13];
    const float* db1  = (const float*)d_in[14];
    const float* dW2  = (const float*)d_in[15];
    const float* db2  = (const float*)d_in[16];
    const float* dW3  = (const float*)d_in[17];
    const float* db3  = (const float*)d_in[18];
    const float* fW1  = (const float*)d_in[19];
    const float* fb1  = (const float*)d_in[20];
    const float* fW2  = (const float*)d_in[21];
    const float* fb2  = (const float*)d_in[22];
    const float* aW1  = (const float*)d_in[23];
    const float* ab1  = (const float*)d_in[24];
    const float* aW2  = (const float*)d_in[25];
    const float* ab2  = (const float*)d_in[26];
    float* out = (float*)d_out;

    char* base = (char*)d_ws;
    size_t o = 0;
    auto alloc = [&](size_t bytes) { char* p = base + o; o += (bytes + 255) & ~size_t(255); return p; };

    int* perm   = (int*)alloc(BATCH * 4);
    int* starts = (int*)alloc((NDOM + 1) * 4);
    float* auxg = (float*)alloc(BATCH * 4);
    unsigned short* XCb  = (unsigned short*)alloc((size_t)BATCH * KP1 * 2);
    unsigned short* H1c  = (unsigned short*)alloc((size_t)BATCH * 512 * 2);
    unsigned short* H1d  = (unsigned short*)alloc((size_t)BATCH * 512 * 2);
    unsigned short* Wc1b = (unsigned short*)alloc((size_t)512 * KP1 * 2);
    unsigned short* Wd1b = (unsigned short*)alloc((size_t)NDOM * 512 * KP1 * 2);
    unsigned short* Wc2b = (unsigned short*)alloc((size_t)256 * 512 * 2);
    unsigned short* Wd2b = (unsigned short*)alloc((size_t)NDOM * 256 * 512 * 2);
    unsigned short* Wc3b = (unsigned short*)alloc((size_t)128 * 256 * 2);
    unsigned short* Wd3b = (unsigned short*)alloc((size_t)NDOM * 128 * 256 * 2);

    // 1) convert + grouping + prep (one launch)
    front<<<NCONV + 1 + BATCH / 4, 256, 0, stream>>>(
        dom, perm, starts, cW1, dW1, cW2, dW2, cW3, dW3,
        Wc1b, Wd1b, Wc2b, Wd2b, Wc3b, Wd3b,
        x, pnw, pnb, demb, crw, crb, aW1, ab1, aW2, ab2, XCb, auxg);

    // 2) L1 chain-fused, counted-vmcnt pipeline
    gemm_l1_fused<<<dim3(NDOM * 16, 8), 256, 0, stream>>>(
        XCb, Wc1b, Wd1b, cb1, db1, H1c, H1d, starts, perm);

    // 3) fused tail: depth-2 counted pipeline (96KB LDS), R3 block decode
    tail_fused<<<NDOM * 128, 256, 0, stream>>>(
        H1c, H1d, Wc2b, Wd2b, cb2, db2, Wc3b, Wd3b, cb3, db3,
        fW1, fb1, fW2, fb2, auxg, perm, starts, out);
}

// Round 8
// 180.067 us; speedup vs baseline: 1.4488x; 1.0758x over previous
//
#include <hip/hip_runtime.h>
#include <math.h>
#include <stdint.h>

#define BATCH 4096
#define FEAT  1024
#define EDIM  16
#define NDOM  8
#define TDIM  1040   // FEAT + EDIM
#define KP1   1088   // TDIM padded to multiple of 64
#define NLAYER 3
#define EPSV  1e-5f

typedef __attribute__((ext_vector_type(8))) short bf16x8;
typedef __attribute__((ext_vector_type(4))) float f32x4;

// s_waitcnt with ONLY vmcnt=N (lgkm/exp unconstrained). gfx9 encoding:
// vmcnt[3:0]=simm[3:0], vmcnt[5:4]=simm[15:14], expcnt=simm[6:4], lgkm=simm[11:8]
#define VMW(N)  __builtin_amdgcn_s_waitcnt((((N)&15)|(((N)>>4)<<14)|(15<<8)|(7<<4)))
// lgkmcnt(0) only (vmcnt=63 i.e. unconstrained, expcnt=7)
#define LGKW0   __builtin_amdgcn_s_waitcnt((15|(3<<14)|(7<<4)))
#define SBAR    __builtin_amdgcn_s_barrier()
#define SCB     __builtin_amdgcn_sched_barrier(0)

__device__ __forceinline__ unsigned short f2bf(float f) {
    union { float f; unsigned int u; } v; v.f = f;
    unsigned int u = v.u;
    return (unsigned short)((u + 0x7fffu + ((u >> 16) & 1u)) >> 16);
}
__device__ __forceinline__ float bf2f(unsigned short u) {
    union { unsigned int u; float f; } v; v.u = ((unsigned int)u) << 16; return v.f;
}
__device__ __forceinline__ void gload_lds16(const void* g, void* l) {
    __builtin_amdgcn_global_load_lds(
        (const __attribute__((address_space(1))) void*)(g),
        (__attribute__((address_space(3))) void*)(l), 16, 0, 0);
}

// 64x64 convert tiles
#define T_W1 136
#define T_W2 32
#define T_W3 8
#define NCONV (T_W1*9 + T_W2*9 + T_W3*9)   // 1584

// ======== kernel 1 "front": converts + grouping + prep (R11-proven) ========
__global__ __launch_bounds__(256) void front(
    const int* __restrict__ dom, int* __restrict__ perm, int* __restrict__ starts,
    const float* __restrict__ cW1, const float* __restrict__ dW1,
    const float* __restrict__ cW2, const float* __restrict__ dW2,
    const float* __restrict__ cW3, const float* __restrict__ dW3,
    unsigned short* __restrict__ Wc1b, unsigned short* __restrict__ Wd1b,
    unsigned short* __restrict__ Wc2b, unsigned short* __restrict__ Wd2b,
    unsigned short* __restrict__ Wc3b, unsigned short* __restrict__ Wd3b,
    const float* __restrict__ x,
    const float* __restrict__ pnw, const float* __restrict__ pnb,
    const float* __restrict__ demb,
    const float* __restrict__ crw, const float* __restrict__ crb,
    const float* __restrict__ aW1, const float* __restrict__ ab1,
    const float* __restrict__ aW2, const float* __restrict__ ab2,
    unsigned short* __restrict__ XCb, float* __restrict__ auxg) {
    int b = blockIdx.x;
    int t = threadIdx.x;

    if (b < NCONV) {
        __shared__ float tile[64][65];
        const float* src; unsigned short* dst; int K, N, Kp, rr;
        if (b < T_W1)            { src = cW1; dst = Wc1b; K = TDIM; N = 512; Kp = KP1; rr = b; }
        else if (b < T_W1*9)     { int r = b - T_W1; int z = r / T_W1; rr = r % T_W1;
                                   src = dW1 + (size_t)z * TDIM * 512; dst = Wd1b + (size_t)z * 512 * KP1;
                                   K = TDIM; N = 512; Kp = KP1; }
        else if (b < T_W1*9+T_W2)   { src = cW2; dst = Wc2b; K = 512; N = 256; Kp = 512; rr = b - T_W1*9; }
        else if (b < T_W1*9+T_W2*9) { int r = b - (T_W1*9+T_W2); int z = r / T_W2; rr = r % T_W2;
                                   src = dW2 + (size_t)z * 512 * 256; dst = Wd2b + (size_t)z * 256 * 512;
                                   K = 512; N = 256; Kp = 512; }
        else if (b < T_W1*9+T_W2*9+T_W3) { src = cW3; dst = Wc3b; K = 256; N = 128; Kp = 256; rr = b - (T_W1*9+T_W2*9); }
        else                     { int r = b - (T_W1*9+T_W2*9+T_W3); int z = r / T_W3; rr = r % T_W3;
                                   src = dW3 + (size_t)z * 256 * 128; dst = Wd3b + (size_t)z * 128 * 256;
                                   K = 256; N = 128; Kp = 256; }
        int kt = Kp >> 6;
        int kb = rr % kt, nb = rr / kt;
        int k0 = kb * 64, n0 = nb * 64;
        #pragma unroll
        for (int i = 0; i < 4; i++) {
            int flat = t + i * 256;
            int kr = flat >> 4, c4 = flat & 15;
            int k = k0 + kr;
            float4 v = make_float4(0.f, 0.f, 0.f, 0.f);
            if (k < K) v = *(const float4*)(src + (size_t)k * N + n0 + c4 * 4);
            tile[kr][c4 * 4 + 0] = v.x;
            tile[kr][c4 * 4 + 1] = v.y;
            tile[kr][c4 * 4 + 2] = v.z;
            tile[kr][c4 * 4 + 3] = v.w;
        }
        __syncthreads();
        #pragma unroll
        for (int i = 0; i < 4; i++) {
            int flat = t + i * 256;
            int n = flat >> 4, kg = flat & 15;
            ushort4 sv;
            sv.x = f2bf(tile[kg * 4 + 0][n]);
            sv.y = f2bf(tile[kg * 4 + 1][n]);
            sv.z = f2bf(tile[kg * 4 + 2][n]);
            sv.w = f2bf(tile[kg * 4 + 3][n]);
            *(ushort4*)(dst + (size_t)(n0 + n) * Kp + k0 + kg * 4) = sv;
        }
        return;
    }
    if (b == NCONV) {
        __shared__ int cnt[NDOM];
        __shared__ int off[NDOM];
        if (t < NDOM) cnt[t] = 0;
        __syncthreads();
        for (int i = t; i < BATCH; i += 256) atomicAdd(&cnt[dom[i]], 1);
        __syncthreads();
        if (t == 0) {
            int s = 0;
            for (int d = 0; d < NDOM; d++) { off[d] = s; starts[d] = s; s += cnt[d]; }
            starts[NDOM] = s;
        }
        __syncthreads();
        for (int i = t; i < BATCH; i += 256) {
            int p = atomicAdd(&off[dom[i]], 1);
            perm[p] = i;
        }
        return;
    }

    // ---- prep: one wave per row, row in registers, barrier-free ----
    int w = t >> 6, lane = t & 63;
    int row = (b - NCONV - 1) * 4 + w;
    int d = dom[row];

    float4 X[4];
    #pragma unroll
    for (int j = 0; j < 4; j++)
        X[j] = *(const float4*)(x + (size_t)row * FEAT + 4 * lane + 256 * j);

    float s = 0.f, ss = 0.f;
    #pragma unroll
    for (int j = 0; j < 4; j++) {
        s  += X[j].x + X[j].y + X[j].z + X[j].w;
        ss += X[j].x*X[j].x + X[j].y*X[j].y + X[j].z*X[j].z + X[j].w*X[j].w;
    }
    #pragma unroll
    for (int m = 1; m < 64; m <<= 1) {
        s  += __shfl_xor(s,  m);
        ss += __shfl_xor(ss, m);
    }
    float mean = s / (float)FEAT;
    float var  = ss / (float)FEAT - mean * mean;
    float rstd = rsqrtf(var + EPSV);

    float4 x0[4], xc[4];
    #pragma unroll
    for (int j = 0; j < 4; j++) {
        float4 wv = *(const float4*)(pnw + (size_t)d * FEAT + 4 * lane + 256 * j);
        float4 bv = *(const float4*)(pnb + (size_t)d * FEAT + 4 * lane + 256 * j);
        x0[j].x = (X[j].x - mean) * rstd * wv.x + bv.x;
        x0[j].y = (X[j].y - mean) * rstd * wv.y + bv.y;
        x0[j].z = (X[j].z - mean) * rstd * wv.z + bv.z;
        x0[j].w = (X[j].w - mean) * rstd * wv.w + bv.w;
        xc[j] = x0[j];
    }
    float x0e = 0.f, xce = 0.f;
    if (lane < EDIM) { x0e = demb[d * EDIM + lane]; xce = x0e; }

    #pragma unroll
    for (int l = 0; l < NLAYER; l++) {
        const float* wl = crw + l * TDIM;
        const float* bl = crb + l * TDIM;
        float partial = 0.f;
        #pragma unroll
        for (int j = 0; j < 4; j++) {
            float4 wv = *(const float4*)(wl + 4 * lane + 256 * j);
            partial += xc[j].x*wv.x + xc[j].y*wv.y + xc[j].z*wv.z + xc[j].w*wv.w;
        }
        if (lane < EDIM) partial += xce * wl[FEAT + lane];
        #pragma unroll
        for (int m = 1; m < 64; m <<= 1) partial += __shfl_xor(partial, m);
        float proj = partial;
        #pragma unroll
        for (int j = 0; j < 4; j++) {
            float4 bv = *(const float4*)(bl + 4 * lane + 256 * j);
            xc[j].x = fmaf(x0[j].x, proj, bv.x + xc[j].x);
            xc[j].y = fmaf(x0[j].y, proj, bv.y + xc[j].y);
            xc[j].z = fmaf(x0[j].z, proj, bv.z + xc[j].z);
            xc[j].w = fmaf(x0[j].w, proj, bv.w + xc[j].w);
        }
        if (lane < EDIM) xce = fmaf(x0e, proj, bl[FEAT + lane] + xce);
    }

    #pragma unroll
    for (int j = 0; j < 4; j++) {
        ushort4 sv;
        sv.x = f2bf(xc[j].x); sv.y = f2bf(xc[j].y);
        sv.z = f2bf(xc[j].z); sv.w = f2bf(xc[j].w);
        *(ushort4*)(XCb + (size_t)row * KP1 + 4 * lane + 256 * j) = sv;
    }
    XCb[(size_t)row * KP1 + FEAT + lane] = (lane < EDIM) ? f2bf(xce) : 0;

    float h = (lane < 32) ? ab1[lane] : 0.f;
    #pragma unroll
    for (int e = 0; e < EDIM; e++) {
        float ev = __shfl(xce, e);
        if (lane < 32) h = fmaf(ev, aW1[e * 32 + lane], h);
    }
    float c = (lane < 32) ? fmaxf(h, 0.f) * aW2[lane] : 0.f;
    #pragma unroll
    for (int m = 1; m < 64; m <<= 1) c += __shfl_xor(c, m);
    if (lane == 0) auxg[row] = c + ab2[0];
}

// ======== L1 GEMM, chain-fused, 64m x 128n, counted-vmcnt pipeline ========
// R7 post-mortem: padded grid put useful blocks on even CU-slots only (2x
// pileup). Now blockIdx.x is a FLAT useful-slot id mapped to (d, m0) via an
// 8-entry walk over starts[] — every launched block is useful, uniform
// round-robin spread (~2/CU).
__global__ __launch_bounds__(256) void gemm_l1_fused(
    const unsigned short* __restrict__ A,    // XCb [BATCH][KP1]
    const unsigned short* __restrict__ Wc,   // Wc1b [512][KP1]
    const unsigned short* __restrict__ Wd,   // Wd1b [D][512][KP1]
    const float* __restrict__ bc, const float* __restrict__ bd,
    unsigned short* __restrict__ Cc, unsigned short* __restrict__ Cd, // perm-space [BATCH][512]
    const int* __restrict__ starts, const int* __restrict__ perm) {
    __shared__ short As[2][64 * 64];    // 2 x 8KB
    __shared__ short Bs[2][128 * 64];   // 2 x 16KB

    // flat slot -> (d, m0): slot g covers 64 rows within one domain
    int g = blockIdx.x;
    int d = 0, acc = 0, m0 = -1, mEnd = 0;
    #pragma unroll
    for (int dd = 0; dd < NDOM; dd++) {
        int c0 = starts[dd], c1 = starts[dd + 1];
        int ns = (c1 - c0 + 63) >> 6;
        if (m0 < 0 && g < acc + ns) { d = dd; m0 = c0 + ((g - acc) << 6); mEnd = c1; }
        acc += ns;
    }
    if (m0 < 0) return;
    int n0 = blockIdx.y * 64;          // column base within each chain's 512

    int tid = threadIdx.x;
    int w = tid >> 6, lane = tid & 63;
    int lr = lane & 15, q = lane >> 4;

    const unsigned short* pA[2]; int sA[2];
    const unsigned short* pB[4]; int sB[4];
    #pragma unroll
    for (int i = 0; i < 2; i++) {
        int seg = i * 4 + w;
        int ch = seg * 64 + lane;
        int loc = ch >> 3, c = ch & 7;
        int mm = m0 + loc; if (mm > mEnd - 1) mm = mEnd - 1;
        int rowp = perm[mm];
        pA[i] = A + (size_t)rowp * KP1 + ((c ^ (loc & 7)) << 3);
        sA[i] = seg * 512;
    }
    #pragma unroll
    for (int i = 0; i < 4; i++) {
        int seg = i * 4 + w;
        int ch = seg * 64 + lane;
        int loc = ch >> 3, c = ch & 7;
        const unsigned short* base = (loc < 64)
            ? (Wc + (size_t)(n0 + loc) * KP1)
            : (Wd + ((size_t)d * 512 + n0 + (loc - 64)) * KP1);
        pB[i] = base + ((c ^ (loc & 7)) << 3);
        sB[i] = seg * 512;
    }

    f32x4 acc4[4][2];
    #pragma unroll
    for (int i = 0; i < 4; i++)
        #pragma unroll
        for (int j = 0; j < 2; j++)
            acc4[i][j] = (f32x4){0.f, 0.f, 0.f, 0.f};

    // prologue: stage k-tile 0 into buffer 0 (6 loads/wave in flight)
    #pragma unroll
    for (int i = 0; i < 2; i++) gload_lds16(pA[i], As[0] + sA[i]);
    #pragma unroll
    for (int i = 0; i < 4; i++) gload_lds16(pB[i], Bs[0] + sB[i]);

    #pragma unroll 1
    for (int ks = 0; ks < KP1 / 64; ks++) {
        int cur = ks & 1, nxt = cur ^ 1;
        if (ks < KP1 / 64 - 1) {
            int k0 = (ks + 1) * 64;
            #pragma unroll
            for (int i = 0; i < 2; i++) gload_lds16(pA[i] + k0, As[nxt] + sA[i]);
            #pragma unroll
            for (int i = 0; i < 4; i++) gload_lds16(pB[i] + k0, Bs[nxt] + sB[i]);
            VMW(6);               // wait tile ks only; ks+1 stays in flight
        } else {
            VMW(0);
        }
        SBAR; SCB;
        #pragma unroll
        for (int half = 0; half < 2; half++) {
            int cc = half * 4 + q;
            bf16x8 af[4], bf[2];
            #pragma unroll
            for (int i = 0; i < 4; i++) {
                int m = i * 16 + lr;
                af[i] = *(const bf16x8*)(As[cur] + m * 64 + ((cc ^ (m & 7)) << 3));
            }
            #pragma unroll
            for (int j = 0; j < 2; j++) {
                int n = w * 32 + j * 16 + lr;
                bf[j] = *(const bf16x8*)(Bs[cur] + n * 64 + ((cc ^ (n & 7)) << 3));
            }
            #pragma unroll
            for (int i = 0; i < 4; i++)
                #pragma unroll
                for (int j = 0; j < 2; j++)
                    acc4[i][j] = __builtin_amdgcn_mfma_f32_16x16x32_bf16(
                        af[i], bf[j], acc4[i][j], 0, 0, 0);
        }
        LGKW0; SBAR; SCB;         // all waves done reading 'cur' -> reusable
    }

    int chain = w >> 1, hn = w & 1;    // waves 0,1 -> center; 2,3 -> domain
    const float* bias = chain ? (bd + d * 512) : bc;
    unsigned short* C = chain ? Cd : Cc;
    #pragma unroll
    for (int i = 0; i < 4; i++) {
        #pragma unroll
        for (int j = 0; j < 2; j++) {
            int col = n0 + hn * 32 + j * 16 + lr;
            float bvv = bias[col];
            int rowb = m0 + i * 16 + q * 4;
            #pragma unroll
            for (int r = 0; r < 4; r++) {
                int row = rowb + r;
                if (row >= mEnd) continue;
                C[(size_t)row * 512 + col] = f2bf(fmaxf(acc4[i][j][r] + bvv, 0.f));
            }
        }
    }
}

// ======== fused tail: L2+L3+STAR+final MLP+sigmoid, depth-2 counted pipeline ====
// Flat useful-slot grid (136 blocks) — no pileup: blockIdx.x walks starts[]
// to find (d, m0). 24 flat stages; 2 x 36KB stage buffers (96KB LDS).
__global__ __launch_bounds__(256) void tail_fused(
    const unsigned short* __restrict__ H1c, const unsigned short* __restrict__ H1d,
    const unsigned short* __restrict__ Wc2, const unsigned short* __restrict__ Wd2,
    const float* __restrict__ cb2v, const float* __restrict__ db2v,
    const unsigned short* __restrict__ Wc3, const unsigned short* __restrict__ Wd3,
    const float* __restrict__ cb3v, const float* __restrict__ db3v,
    const float* __restrict__ fW1, const float* __restrict__ fb1,
    const float* __restrict__ fW2, const float* __restrict__ fb2,
    const float* __restrict__ auxg, const int* __restrict__ perm,
    const int* __restrict__ starts, float* __restrict__ out) {

    __shared__ __align__(16) char smem[98304];   // 96KB (proven)
    short* BufB[2]; short* BufA[2];
    #pragma unroll
    for (int i = 0; i < 2; i++) {
        BufB[i] = (short*)(smem + i * 36864);            // 32KB B tile
        BufA[i] = (short*)(smem + i * 36864 + 32768);    // 4KB  A tile
    }
    short* H2    = (short*)(smem + 73728);               // 16KB [32][256] swizzled
    short* fused = (short*)(smem + 90112);               // 8KB  [32][128] swizzled

    // flat slot -> (d, m0): slot g covers 32 rows within one domain
    int g = blockIdx.x;
    int d = 0, acc = 0, m0 = -1, mEnd = 0;
    #pragma unroll
    for (int dd = 0; dd < NDOM; dd++) {
        int c0 = starts[dd], c1 = starts[dd + 1];
        int ns = (c1 - c0 + 31) >> 5;
        if (m0 < 0 && g < acc + ns) { d = dd; m0 = c0 + ((g - acc) << 5); mEnd = c1; }
        acc += ns;
    }
    if (m0 < 0) return;

    int tid = threadIdx.x;
    int w = tid >> 6, lane = tid & 63;
    int lr = lane & 15, q = lane >> 4;

    int bn = w * 8 + (lane >> 3);
    int sw = ((lane & 7) ^ (bn & 7)) << 3;
    int rowA = m0 + bn; if (rowA > mEnd - 1) rowA = mEnd - 1;

    const unsigned short* pA0  = H1c + (size_t)rowA * 512 + sw;
    const unsigned short* pA1  = H1d + (size_t)rowA * 512 + sw;
    const unsigned short* pW20 = Wc2 + (size_t)bn * 512 + sw;
    const unsigned short* pW21 = Wd2 + (size_t)d * 256 * 512 + (size_t)bn * 512 + sw;
    const unsigned short* pW30 = Wc3 + (size_t)bn * 256 + sw;
    const unsigned short* pW31 = Wd3 + (size_t)d * 128 * 256 + (size_t)bn * 256 + sw;

    // stage s (0..23): c=s/12, k=s%12. k<8: L2 (9 loads/wave), else L3 (4).
    auto istep = [&](int s) {
        int c = s / 12, k = s % 12, b = s & 1;
        if (k < 8) {
            const unsigned short* pa = c ? pA1 : pA0;
            const unsigned short* pw = c ? pW21 : pW20;
            int k0 = k * 64;
            gload_lds16(pa + k0, BufA[b] + w * 512);
            #pragma unroll
            for (int i = 0; i < 8; i++)
                gload_lds16(pw + (size_t)i * 32 * 512 + k0, BufB[b] + (i * 4 + w) * 512);
        } else {
            const unsigned short* pw = c ? pW31 : pW30;
            int k0 = (k - 8) * 64;
            #pragma unroll
            for (int i = 0; i < 4; i++)
                gload_lds16(pw + (size_t)i * 32 * 256 + k0, BufB[b] + (i * 4 + w) * 512);
        }
    };

    f32x4 acc2[2][4], acc3[2][2];

    auto cstep = [&](int s) {
        int c = s / 12, k = s % 12, b = s & 1;
        if (k < 8) {
            if (k == 0) {
                #pragma unroll
                for (int i = 0; i < 2; i++)
                    #pragma unroll
                    for (int j = 0; j < 4; j++) acc2[i][j] = (f32x4){0.f, 0.f, 0.f, 0.f};
            }
            #pragma unroll
            for (int half = 0; half < 2; half++) {
                int cc = half * 4 + q;
                bf16x8 af[2], bf[4];
                #pragma unroll
                for (int i = 0; i < 2; i++) {
                    int m = i * 16 + lr;
                    af[i] = *(const bf16x8*)(BufA[b] + m * 64 + ((cc ^ (m & 7)) << 3));
                }
                #pragma unroll
                for (int j = 0; j < 4; j++) {
                    int n = w * 64 + j * 16 + lr;
                    bf[j] = *(const bf16x8*)(BufB[b] + n * 64 + ((cc ^ (n & 7)) << 3));
                }
                #pragma unroll
                for (int i = 0; i < 2; i++)
                    #pragma unroll
                    for (int j = 0; j < 4; j++)
                        acc2[i][j] = __builtin_amdgcn_mfma_f32_16x16x32_bf16(
                            af[i], bf[j], acc2[i][j], 0, 0, 0);
            }
            if (k == 7) {   // L2 epilogue -> H2 (swizzled)
                const float* b2 = c ? (db2v + d * 256) : cb2v;
                #pragma unroll
                for (int i = 0; i < 2; i++)
                    #pragma unroll
                    for (int j = 0; j < 4; j++) {
                        int col = w * 64 + j * 16 + lr;
                        float bv = b2[col];
                        int cch = col >> 3;
                        #pragma unroll
                        for (int r = 0; r < 4; r++) {
                            int row = i * 16 + q * 4 + r;
                            int pc = (cch & 24) | ((cch ^ (row & 7)) & 7);
                            float v = fmaxf(acc2[i][j][r] + bv, 0.f);
                            H2[row * 256 + pc * 8 + (col & 7)] = (short)f2bf(v);
                        }
                    }
            }
        } else {
            int it = k - 8;
            if (it == 0) {
                #pragma unroll
                for (int i = 0; i < 2; i++)
                    #pragma unroll
                    for (int j = 0; j < 2; j++) acc3[i][j] = (f32x4){0.f, 0.f, 0.f, 0.f};
            }
            #pragma unroll
            for (int half = 0; half < 2; half++) {
                int cc = half * 4 + q;
                int C = it * 8 + cc;
                bf16x8 af[2], bf[2];
                #pragma unroll
                for (int i = 0; i < 2; i++) {
                    int m = i * 16 + lr;
                    int pcm = (C & 24) | ((C ^ (m & 7)) & 7);
                    af[i] = *(const bf16x8*)(H2 + m * 256 + pcm * 8);
                }
                #pragma unroll
                for (int j = 0; j < 2; j++) {
                    int n = w * 32 + j * 16 + lr;
                    bf[j] = *(const bf16x8*)(BufB[b] + n * 64 + ((cc ^ (n & 7)) << 3));
                }
                #pragma unroll
                for (int i = 0; i < 2; i++)
                    #pragma unroll
                    for (int j = 0; j < 2; j++)
                        acc3[i][j] = __builtin_amdgcn_mfma_f32_16x16x32_bf16(
                            af[i], bf[j], acc3[i][j], 0, 0, 0);
            }
            if (it == 3) {   // L3 epilogue -> fused
                const float* b3 = c ? (db3v + d * 128) : cb3v;
                #pragma unroll
                for (int i = 0; i < 2; i++)
                    #pragma unroll
                    for (int j = 0; j < 2; j++) {
                        int col = w * 32 + j * 16 + lr;
                        float bv = b3[col];
                        int cch = col >> 3;
                        #pragma unroll
                        for (int r = 0; r < 4; r++) {
                            int row = i * 16 + q * 4 + r;
                            int pc = (cch & 8) | ((cch ^ (row & 7)) & 7);
                            int idx = row * 128 + pc * 8 + (col & 7);
                            if (c == 0) {
                                fused[idx] = (short)f2bf(acc3[i][j][r] + bv);
                            } else {
                                float cv = bf2f((unsigned short)fused[idx]);
                                fused[idx] = (short)f2bf(cv * tanhf(acc3[i][j][r] + bv));
                            }
                        }
                    }
            }
        }
    };

    // TSTEP(S,N): N = loads(S+1) — stage S+1 stays in flight across barriers.
    #define TSTEP(S, NW) do { \
        VMW(NW); SBAR; SCB; \
        cstep(S); \
        LGKW0; SBAR; SCB; \
        if ((S) + 2 < 24) istep((S) + 2); \
    } while (0)

    // prologue: stages 0,1 in flight
    istep(0); istep(1);

    TSTEP(0, 9);   TSTEP(1, 9);   TSTEP(2, 9);   TSTEP(3, 9);
    TSTEP(4, 9);   TSTEP(5, 9);   TSTEP(6, 9);   TSTEP(7, 4);
    TSTEP(8, 4);   TSTEP(9, 4);   TSTEP(10, 4);  TSTEP(11, 9);
    TSTEP(12, 9);  TSTEP(13, 9);  TSTEP(14, 9);  TSTEP(15, 9);
    TSTEP(16, 9);  TSTEP(17, 9);  TSTEP(18, 9);  TSTEP(19, 4);
    TSTEP(20, 4);  TSTEP(21, 4);  TSTEP(22, 4);  TSTEP(23, 0);
    #undef TSTEP

    __syncthreads();   // vmcnt already 0; full fence before buffer reuse

    // ---- final MLP (R7-proven epilogue): (32x128)@(128x64) relu @ (64x1) + sigmoid ----
    short* Bsf = BufB[0];
    float* Ls  = (float*)BufA[0];
    for (int s2 = tid; s2 < 1024; s2 += 256) {
        int n = s2 >> 4, cch = s2 & 15;
        bf16x8 vv;
        #pragma unroll
        for (int kk = 0; kk < 8; kk++)
            vv[kk] = (short)f2bf(fW1[(cch * 8 + kk) * 64 + n]);
        int pc = (cch & 8) | ((cch ^ (n & 7)) & 7);
        *(bf16x8*)(Bsf + n * 128 + pc * 8) = vv;
    }
    __syncthreads();

    int wm = w >> 1, wn = w & 1;
    f32x4 acc2f[2];
    #pragma unroll
    for (int j = 0; j < 2; j++) acc2f[j] = (f32x4){0.f, 0.f, 0.f, 0.f};
    #pragma unroll
    for (int g2 = 0; g2 < 4; g2++) {
        int cc = g2 * 4 + q;
        int m = wm * 16 + lr;
        int pcm = (cc & 8) | ((cc ^ (m & 7)) & 7);
        bf16x8 af = *(const bf16x8*)(fused + m * 128 + pcm * 8);
        #pragma unroll
        for (int j = 0; j < 2; j++) {
            int n = wn * 32 + j * 16 + lr;
            int pcn = (cc & 8) | ((cc ^ (n & 7)) & 7);
            bf16x8 bf = *(const bf16x8*)(Bsf + n * 128 + pcn * 8);
            acc2f[j] = __builtin_amdgcn_mfma_f32_16x16x32_bf16(af, bf, acc2f[j], 0, 0, 0);
        }
    }

    float w2v[2], b1v[2];
    #pragma unroll
    for (int j = 0; j < 2; j++) {
        int col = wn * 32 + j * 16 + lr;
        w2v[j] = fW2[col];
        b1v[j] = fb1[col];
    }
    float rowv[4];
    #pragma unroll
    for (int r = 0; r < 4; r++) {
        float v = 0.f;
        #pragma unroll
        for (int j = 0; j < 2; j++)
            v += fmaxf(acc2f[j][r] + b1v[j], 0.f) * w2v[j];
        v += __shfl_xor(v, 1);
        v += __shfl_xor(v, 2);
        v += __shfl_xor(v, 4);
        v += __shfl_xor(v, 8);
        rowv[r] = v;
    }
    if (wn == 0 && lr == 0) {
        #pragma unroll
        for (int r = 0; r < 4; r++)
            Ls[wm * 16 + q * 4 + r] = rowv[r];
    }
    __syncthreads();
    if (wn == 1 && lr == 0) {
        float b2 = fb2[0];
        #pragma unroll
        for (int r = 0; r < 4; r++) {
            int row = wm * 16 + q * 4 + r;
            int p = m0 + row;
            if (p < mEnd) {
                int orow = perm[p];
                float logit = Ls[row] + rowv[r] + b2 + auxg[orow];
                out[orow] = 1.f / (1.f + expf(-logit));
            }
        }
    }
}

extern "C" void kernel_launch(void* const* d_in, const int* in_sizes, int n_in,
                              void* d_out, int out_size, void* d_ws, size_t ws_size,
                              hipStream_t stream) {
    (void)in_sizes; (void)n_in; (void)out_size; (void)ws_size;

    const float* x    = (const float*)d_in[0];
    const int*   dom  = (const int*)  d_in[1];
    const float* pnw  = (const float*)d_in[2];
    const float* pnb  = (const float*)d_in[3];
    const float* demb = (const float*)d_in[4];
    const float* crw  = (const float*)d_in[5];
    const float* crb  = (const float*)d_in[6];
    const float* cW1  = (const float*)d_in[7];
    const float* cb1  = (const float*)d_in[8];
    const float* cW2  = (const float*)d_in[9];
    const float* cb2  = (const float*)d_in[10];
    const float* cW3  = (const float*)d_in[11];
    const float* cb3  = (const float*)d_in[12];
    const float* dW1  = (const float*)d_in[13];
    const float* db1  = (const float*)d_in[14];
    const float* dW2  = (const float*)d_in[15];
    const float* db2  = (const float*)d_in[16];
    const float* dW3  = (const float*)d_in[17];
    const float* db3  = (const float*)d_in[18];
    const float* fW1  = (const float*)d_in[19];
    const float* fb1  = (const float*)d_in[20];
    const float* fW2  = (const float*)d_in[21];
    const float* fb2  = (const float*)d_in[22];
    const float* aW1  = (const float*)d_in[23];
    const float* ab1  = (const float*)d_in[24];
    const float* aW2  = (const float*)d_in[25];
    const float* ab2  = (const float*)d_in[26];
    float* out = (float*)d_out;

    char* base = (char*)d_ws;
    size_t o = 0;
    auto alloc = [&](size_t bytes) { char* p = base + o; o += (bytes + 255) & ~size_t(255); return p; };

    int* perm   = (int*)alloc(BATCH * 4);
    int* starts = (int*)alloc((NDOM + 1) * 4);
    float* auxg = (float*)alloc(BATCH * 4);
    unsigned short* XCb  = (unsigned short*)alloc((size_t)BATCH * KP1 * 2);
    unsigned short* H1c  = (unsigned short*)alloc((size_t)BATCH * 512 * 2);
    unsigned short* H1d  = (unsigned short*)alloc((size_t)BATCH * 512 * 2);
    unsigned short* Wc1b = (unsigned short*)alloc((size_t)512 * KP1 * 2);
    unsigned short* Wd1b = (unsigned short*)alloc((size_t)NDOM * 512 * KP1 * 2);
    unsigned short* Wc2b = (unsigned short*)alloc((size_t)256 * 512 * 2);
    unsigned short* Wd2b = (unsigned short*)alloc((size_t)NDOM * 256 * 512 * 2);
    unsigned short* Wc3b = (unsigned short*)alloc((size_t)128 * 256 * 2);
    unsigned short* Wd3b = (unsigned short*)alloc((size_t)NDOM * 128 * 256 * 2);

    // 1) convert + grouping + prep (one launch)
    front<<<NCONV + 1 + BATCH / 4, 256, 0, stream>>>(
        dom, perm, starts, cW1, dW1, cW2, dW2, cW3, dW3,
        Wc1b, Wd1b, Wc2b, Wd2b, Wc3b, Wd3b,
        x, pnw, pnb, demb, crw, crb, aW1, ab1, aW2, ab2, XCb, auxg);

    // 2) L1 chain-fused: flat useful-slot grid (<=72 slots x 8 n-blocks)
    gemm_l1_fused<<<dim3(72, 8), 256, 0, stream>>>(
        XCb, Wc1b, Wd1b, cb1, db1, H1c, H1d, starts, perm);

    // 3) fused tail: flat useful-slot grid (<=136 slots), depth-2 pipeline
    tail_fused<<<136, 256, 0, stream>>>(
        H1c, H1d, Wc2b, Wd2b, cb2, db2, Wc3b, Wd3b, cb3, db3,
        fW1, fb1, fW2, fb2, auxg, perm, starts, out);
}